// Round 8
// baseline (296.045 us; speedup 1.0000x reference)
//
#include <hip/hip_runtime.h>
#include <math.h>

#define NN 100000      // nodes
#define DD 64          // dim
#define NE 1200000     // edges (without self-loops)
#define NB 391         // buckets of 256 nodes
#define SCH 2048       // edges per scatter block
#define GB ((NN + 63) / 64)   // 1563 row tiles for GEMM
#define HS 88          // LDS row stride in shorts (176B: 16B-aligned, <=2-way banks)

typedef __attribute__((ext_vector_type(8))) short bf16x8;
typedef __attribute__((ext_vector_type(4))) float f32x4;

__device__ __forceinline__ unsigned short f2bf(float x) {
    unsigned u = __float_as_uint(x);
    return (unsigned short)((u + 0x7FFFu + ((u >> 16) & 1u)) >> 16);   // RNE
}
__device__ __forceinline__ float bf2f(unsigned short b) {
    return __uint_as_float(((unsigned)b) << 16);
}

__device__ __forceinline__ float gelu_exact(float x) {
    return 0.5f * x * (1.0f + erff(x * 0.70710678118654752f));
}

__device__ __forceinline__ float leaky(float x) {
    return fmaxf(x, 0.f) + 0.2f * fminf(x, 0.f);
}

// ---------------- CSR build: two-level bucket sort (self-loops embedded) ----------------

__global__ __launch_bounds__(256) void k_bcount(const int* __restrict__ tgt, int* __restrict__ bcnt) {
    __shared__ int h[NB];
    for (int i = threadIdx.x; i < NB; i += 256) h[i] = 0;
    __syncthreads();
    const int stride = gridDim.x * 256;
    for (int i = blockIdx.x * 256 + threadIdx.x; i < NE; i += stride)
        atomicAdd(&h[tgt[i] >> 8], 1);
    __syncthreads();
    for (int i = threadIdx.x; i < NB; i += 256)
        if (h[i]) atomicAdd(&bcnt[i], h[i]);
}

__global__ __launch_bounds__(512) void k_bscan(const int* __restrict__ bcnt,
                                               int* __restrict__ bbase, int* __restrict__ wbase) {
    __shared__ int s[512];
    const int tid = threadIdx.x;
    const int v = (tid < NB) ? bcnt[tid] : 0;
    s[tid] = v;
    __syncthreads();
    for (int o = 1; o < 512; o <<= 1) {
        int t = (tid >= o) ? s[tid - o] : 0;
        __syncthreads();
        s[tid] += t;
        __syncthreads();
    }
    if (tid < NB) {
        int ex = s[tid] - v;
        bbase[tid] = ex;
        wbase[tid] = ex;
    }
    if (tid == NB - 1) bbase[NB] = s[tid];   // = NE
}

__global__ __launch_bounds__(256) void k_bscatter(const int* __restrict__ src, const int* __restrict__ tgt,
                                                  int* __restrict__ wbase, unsigned int* __restrict__ ebuf) {
    __shared__ int stgt[SCH];
    __shared__ unsigned short srk[SCH];
    __shared__ int hist[NB];
    __shared__ int hbase[NB];
    const int base = blockIdx.x * SCH;
    const int cnt = min(SCH, NE - base);
    const int tid = threadIdx.x;
    for (int i = tid; i < NB; i += 256) hist[i] = 0;
    for (int i = tid; i < cnt; i += 256) stgt[i] = tgt[base + i];
    __syncthreads();
    for (int i = tid; i < cnt; i += 256)
        srk[i] = (unsigned short)atomicAdd(&hist[stgt[i] >> 8], 1);
    __syncthreads();
    for (int b = tid; b < NB; b += 256) {
        int c = hist[b];
        hbase[b] = c ? atomicAdd(&wbase[b], c) : 0;
    }
    __syncthreads();
    for (int i = tid; i < cnt; i += 256) {
        int t = stgt[i];
        unsigned int e = ((unsigned int)src[base + i] << 8) | (unsigned int)(t & 255);
        ebuf[hbase[t >> 8] + (int)srk[i]] = e;
    }
}

__global__ __launch_bounds__(256) void k_bfinal(const int* __restrict__ bbase,
                                                const unsigned int* __restrict__ ebuf,
                                                int* __restrict__ rowptr, int* __restrict__ csr) {
    __shared__ int hist[256];
    __shared__ int pos[256];
    __shared__ int wsum[4];
    const int b = blockIdx.x, tid = threadIdx.x;
    const int bb = bbase[b], be = bbase[b + 1];
    hist[tid] = 0;
    __syncthreads();
    for (int i = bb + tid; i < be; i += 256) atomicAdd(&hist[ebuf[i] & 255u], 1);
    __syncthreads();
    const int v = hist[tid];
    const int lane = tid & 63, w = tid >> 6;
    int sc = v;
    #pragma unroll
    for (int o = 1; o < 64; o <<= 1) { int t = __shfl_up(sc, o, 64); if (lane >= o) sc += t; }
    if (lane == 63) wsum[w] = sc;
    __syncthreads();
    int off = 0;
    for (int k = 0; k < w; ++k) off += wsum[k];
    const int node = b * 256 + tid;
    const int rp = bb + off + sc - v + node;     // +node: one self slot per preceding node
    if (node < NN) {
        rowptr[node] = rp;
        csr[rp] = node;                          // self-loop first
    } else if (node == NN) {
        rowptr[NN] = rp;                         // = NE + NN
    }
    pos[tid] = rp + 1;                           // edges start after self
    __syncthreads();
    for (int i = bb + tid; i < be; i += 256) {
        unsigned int e = ebuf[i];
        int p = atomicAdd(&pos[e & 255u], 1);
        csr[p] = (int)(e >> 8);
    }
}

// ---------------- weight precompute: A = diag(g)W (bf16 hi/lo), S = g@W, C = beta@W ----------------
__global__ __launch_bounds__(128) void k_wprep(
    const float* __restrict__ Wl, const float* __restrict__ Wr,
    const float* __restrict__ g, const float* __restrict__ be,
    unsigned short* __restrict__ aT, float* __restrict__ S, float* __restrict__ C)
{
    const int c = threadIdx.x;          // 0..127
    const float* W = (c < 64) ? Wl : Wr;
    const int cc = c & 63;
    float s = 0.f, cC = 0.f;
    unsigned short* hi_p = aT + c * 64;
    unsigned short* lo_p = aT + 128 * 64 + c * 64;
    #pragma unroll 8
    for (int k = 0; k < 64; ++k) {
        float w = W[k * 64 + cc];
        float a = g[k] * w;
        unsigned short hi = f2bf(a);
        unsigned short lo = f2bf(a - bf2f(hi));
        hi_p[k] = hi; lo_p[k] = lo;
        s += a;
        cC = fmaf(be[k], w, cC);
    }
    S[c] = s; C[c] = cC;
}

__global__ __launch_bounds__(64) void k_wfinal(
    const float* __restrict__ pw, const float* __restrict__ pb,
    unsigned short* __restrict__ fT, float* __restrict__ Cf)
{
    const int c = threadIdx.x;  // 0..63
    unsigned short* hi_p = fT + c * 64;
    unsigned short* lo_p = fT + 64 * 64 + c * 64;
    #pragma unroll 8
    for (int k = 0; k < 64; ++k) {
        float w = pw[k * 64 + c];
        unsigned short hi = f2bf(w);
        unsigned short lo = f2bf(w - bf2f(hi));
        hi_p[k] = hi; lo_p[k] = lo;
    }
    Cf[c] = pb[c];
}

// ---------------- MFMA node GEMM ----------------
// LN=true: out = rho*(h@A) - rho*mean*S + C; cols<64 -> xlb (bf16), cols>=64 -> xr (fp32).
// LN=false: out = h@A + C -> outp fp32 (in-place safe per 64-row tile).
template<int CTW, bool LN>
__global__ __launch_bounds__(256) void k_gemm(
    const float* __restrict__ h, const unsigned short* __restrict__ aT,
    const float* __restrict__ S, const float* __restrict__ C,
    unsigned short* __restrict__ xlb, float* __restrict__ xr, float* __restrict__ outp)
{
    __shared__ __align__(16) unsigned short hbh[64 * HS];
    __shared__ __align__(16) unsigned short hbl[64 * HS];
    __shared__ float smean[64], srho[64];
    const int tid = threadIdx.x;
    const int tile = blockIdx.x * 64;
    {
        const int row = tid >> 2, q = tid & 3;
        const int node = min(tile + row, NN - 1);
        const float* hp = h + (size_t)node * DD + q * 16;
        float4 v[4];
        #pragma unroll
        for (int i = 0; i < 4; ++i) v[i] = *(const float4*)(hp + i * 4);
        if (LN) {
            float sum = 0.f, ssq = 0.f;
            #pragma unroll
            for (int i = 0; i < 4; ++i) {
                sum += v[i].x + v[i].y + v[i].z + v[i].w;
                ssq += v[i].x * v[i].x + v[i].y * v[i].y + v[i].z * v[i].z + v[i].w * v[i].w;
            }
            sum += __shfl_xor(sum, 1, 64); ssq += __shfl_xor(ssq, 1, 64);
            sum += __shfl_xor(sum, 2, 64); ssq += __shfl_xor(ssq, 2, 64);
            if (q == 0) {
                float mean = sum * 0.015625f;
                float var = ssq * 0.015625f - mean * mean;
                smean[row] = mean;
                srho[row] = rsqrtf(var + 1e-5f);
            }
        }
        #pragma unroll
        for (int half = 0; half < 2; ++half) {
            bf16x8 ph, pl;
            #pragma unroll
            for (int e = 0; e < 8; ++e) {
                float f = (&v[half * 2 + (e >> 2)].x)[e & 3];
                unsigned short hi = f2bf(f);
                unsigned short lo = f2bf(f - bf2f(hi));
                ph[e] = (short)hi; pl[e] = (short)lo;
            }
            const int so = row * HS + q * 16 + half * 8;
            *(bf16x8*)&hbh[so] = ph;
            *(bf16x8*)&hbl[so] = pl;
        }
    }
    __syncthreads();
    const int lane = tid & 63;
    const int wslot = tid >> 6;
    const int li16 = lane & 15;
    const int g16 = lane >> 4;
    const int NCT = CTW * 4;
    f32x4 acc[CTW][4];
    #pragma unroll
    for (int c = 0; c < CTW; ++c)
        #pragma unroll
        for (int rt = 0; rt < 4; ++rt) acc[c][rt] = (f32x4){0.f, 0.f, 0.f, 0.f};
    #pragma unroll
    for (int kk = 0; kk < 2; ++kk) {
        bf16x8 ah[4], al[4];
        #pragma unroll
        for (int rt = 0; rt < 4; ++rt) {
            const int so = (rt * 16 + li16) * HS + kk * 32 + g16 * 8;
            ah[rt] = *(const bf16x8*)&hbh[so];
            al[rt] = *(const bf16x8*)&hbl[so];
        }
        #pragma unroll
        for (int c = 0; c < CTW; ++c) {
            const int ct = wslot + c * 4;
            const unsigned short* bp = aT + (ct * 16 + li16) * 64 + kk * 32 + g16 * 8;
            bf16x8 bh = *(const bf16x8*)bp;
            bf16x8 bl = *(const bf16x8*)(bp + NCT * 16 * 64);
            #pragma unroll
            for (int rt = 0; rt < 4; ++rt) {
                acc[c][rt] = __builtin_amdgcn_mfma_f32_16x16x32_bf16(ah[rt], bh, acc[c][rt], 0, 0, 0);
                acc[c][rt] = __builtin_amdgcn_mfma_f32_16x16x32_bf16(al[rt], bh, acc[c][rt], 0, 0, 0);
                acc[c][rt] = __builtin_amdgcn_mfma_f32_16x16x32_bf16(ah[rt], bl, acc[c][rt], 0, 0, 0);
            }
        }
    }
    #pragma unroll
    for (int c = 0; c < CTW; ++c) {
        const int ct = wslot + c * 4;
        const int col = ct * 16 + li16;
        const float Cc = C[col];
        float Sc = 0.f;
        if (LN) Sc = S[col];
        #pragma unroll
        for (int rt = 0; rt < 4; ++rt) {
            const int r0 = rt * 16 + g16 * 4;
            #pragma unroll
            for (int j = 0; j < 4; ++j) {
                const int row2 = r0 + j;
                const int node = tile + row2;
                if (node < NN) {
                    float p = acc[c][rt][j];
                    if (LN) {
                        float val = fmaf(srho[row2], p - smean[row2] * Sc, Cc);
                        if (ct < 4) xlb[(size_t)node * DD + col]       = f2bf(val);
                        else        xr[(size_t)node * DD + (col & 63)] = val;
                    } else {
                        outp[(size_t)node * DD + col] = p + Cc;
                    }
                }
            }
        }
    }
}

// ---------------- aggregation: one wave per target node, 8 lanes x 8 edges, bf16 gather ----------------
__global__ __launch_bounds__(256) void k_agg(
    const int* __restrict__ rowptr, const int* __restrict__ csr,
    const unsigned short* __restrict__ xlb, const float* __restrict__ xr,
    const float* __restrict__ att, const float* __restrict__ cbias,
    const float* __restrict__ h_in, float* __restrict__ h_out)
{
    const int lane = threadIdx.x & 63;
    const int li   = lane & 7;      // feature-octet index (8 features)
    const int sub  = lane >> 3;     // edge slot 0..7
    const int wid  = (blockIdx.x * 256 + threadIdx.x) >> 6;
    const int nw   = gridDim.x * 4;
    float a[8], xrt[8];
    {
        const float4 a0 = *(const float4*)&att[li * 8];
        const float4 a1 = *(const float4*)&att[li * 8 + 4];
        a[0]=a0.x; a[1]=a0.y; a[2]=a0.z; a[3]=a0.w;
        a[4]=a1.x; a[5]=a1.y; a[6]=a1.z; a[7]=a1.w;
    }
    const float4 cb0 = *(const float4*)&cbias[li * 8];
    const float4 cb1 = *(const float4*)&cbias[li * 8 + 4];
    for (int n = wid; n < NN; n += nw) {
        {
            const float4 x0 = *(const float4*)&xr[(size_t)n * DD + li * 8];
            const float4 x1 = *(const float4*)&xr[(size_t)n * DD + li * 8 + 4];
            xrt[0]=x0.x; xrt[1]=x0.y; xrt[2]=x0.z; xrt[3]=x0.w;
            xrt[4]=x1.x; xrt[5]=x1.y; xrt[6]=x1.z; xrt[7]=x1.w;
        }
        const int beg = rowptr[n], end = rowptr[n + 1];   // len >= 1 (self first)
        const int end1 = end - 1;
        int j  = beg + sub;
        int jc = min(j, end1);
        int s  = csr[jc];
        bf16x8 v = *(const bf16x8*)&xlb[(size_t)s * DD + li * 8];
        float  den = 0.f;
        float  acc[8] = {0.f,0.f,0.f,0.f,0.f,0.f,0.f,0.f};
        const int nch = (end - beg + 7) >> 3;
        for (int c = 0; c < nch; ++c) {
            bf16x8 curp = v;
            const int jcur = j;
            j += 8;
            jc = min(j, end1);
            s  = csr[jc];
            v  = *(const bf16x8*)&xlb[(size_t)s * DD + li * 8];   // unconditional prefetch
            float f[8];
            #pragma unroll
            for (int i = 0; i < 8; ++i) f[i] = bf2f((unsigned short)curp[i]);
            float p = leaky(f[0] + xrt[0]) * a[0];
            #pragma unroll
            for (int i = 1; i < 8; ++i) p = fmaf(leaky(f[i] + xrt[i]), a[i], p);
            p += __shfl_xor(p, 1, 64);
            p += __shfl_xor(p, 2, 64);
            p += __shfl_xor(p, 4, 64);
            float ex = (jcur < end) ? __expf(p) : 0.f;
            den += ex;
            #pragma unroll
            for (int i = 0; i < 8; ++i) acc[i] = fmaf(ex, f[i], acc[i]);
        }
        // reduce across the 8 edge slots
        #pragma unroll
        for (int o = 8; o < 64; o <<= 1) {
            #pragma unroll
            for (int i = 0; i < 8; ++i) acc[i] += __shfl_xor(acc[i], o, 64);
            den += __shfl_xor(den, o, 64);
        }
        if (sub == 0) {
            const float id = 1.f / (den + 1e-16f);
            const float4 hi0 = *(const float4*)&h_in[(size_t)n * DD + li * 8];
            const float4 hi1 = *(const float4*)&h_in[(size_t)n * DD + li * 8 + 4];
            float4 o0, o1;
            o0.x = gelu_exact(fmaf(acc[0], id, cb0.x)) + hi0.x;
            o0.y = gelu_exact(fmaf(acc[1], id, cb0.y)) + hi0.y;
            o0.z = gelu_exact(fmaf(acc[2], id, cb0.z)) + hi0.z;
            o0.w = gelu_exact(fmaf(acc[3], id, cb0.w)) + hi0.w;
            o1.x = gelu_exact(fmaf(acc[4], id, cb1.x)) + hi1.x;
            o1.y = gelu_exact(fmaf(acc[5], id, cb1.y)) + hi1.y;
            o1.z = gelu_exact(fmaf(acc[6], id, cb1.z)) + hi1.z;
            o1.w = gelu_exact(fmaf(acc[7], id, cb1.w)) + hi1.w;
            *(float4*)&h_out[(size_t)n * DD + li * 8]     = o0;
            *(float4*)&h_out[(size_t)n * DD + li * 8 + 4] = o1;
        }
    }
}

extern "C" void kernel_launch(void* const* d_in, const int* in_sizes, int n_in,
                              void* d_out, int out_size, void* d_ws, size_t ws_size,
                              hipStream_t stream) {
    const int*   edge_index = (const int*)d_in[1];
    const int*   src   = edge_index;
    const int*   tgt   = edge_index + NE;
    const float* emb   = (const float*)d_in[2];
    const float* ln_g  = (const float*)d_in[3];
    const float* ln_b  = (const float*)d_in[4];
    const float* Wl    = (const float*)d_in[5];
    const float* Wr    = (const float*)d_in[6];
    const float* att   = (const float*)d_in[7];
    const float* cbias = (const float*)d_in[8];
    const float* pw    = (const float*)d_in[9];
    const float* pb    = (const float*)d_in[10];
    float* out = (float*)d_out;

    unsigned short* xlb = (unsigned short*)d_ws;           // NN*64 bf16
    float* xr = (float*)(xlb + (size_t)NN * DD);
    int* csr             = (int*)(xr + (size_t)NN * DD);   // NE+NN
    unsigned int* ebuf   = (unsigned int*)(csr + NE + NN);
    int* rowptr          = (int*)(ebuf + NE);              // NN+8
    int* bcnt            = rowptr + NN + 8;                // 392 (padded)
    int* bbase           = bcnt + 392;                     // 400 (padded)
    int* wbase           = bbase + 400;                    // 400 (padded)
    unsigned short* aT0  = (unsigned short*)(wbase + 400); // 2*128*64
    unsigned short* aT1  = aT0 + 2 * 128 * 64;
    unsigned short* fT   = aT1 + 2 * 128 * 64;             // 2*64*64
    float* S0 = (float*)(fT + 2 * 64 * 64);
    float* C0 = S0 + 128;
    float* S1 = C0 + 128;
    float* C1 = S1 + 128;
    float* Cf = C1 + 128;

    const int AGG_BLOCKS = 2048;

    // ---- weight precompute (tiny) ----
    k_wprep<<<1, 128, 0, stream>>>(Wl, Wr, ln_g, ln_b, aT0, S0, C0);
    k_wprep<<<1, 128, 0, stream>>>(Wl + DD * DD, Wr + DD * DD, ln_g + DD, ln_b + DD, aT1, S1, C1);
    k_wfinal<<<1, 64, 0, stream>>>(pw, pb, fT, Cf);

    // ---- CSR build (two-level bucket sort by target, self-loops embedded) ----
    hipMemsetAsync(bcnt, 0, NB * sizeof(int), stream);
    k_bcount<<<256, 256, 0, stream>>>(tgt, bcnt);
    k_bscan<<<1, 512, 0, stream>>>(bcnt, bbase, wbase);
    k_bscatter<<<(NE + SCH - 1) / SCH, 256, 0, stream>>>(src, tgt, wbase, ebuf);
    k_bfinal<<<NB, 256, 0, stream>>>(bbase, ebuf, rowptr, csr);

    // ---- layer 0 ----
    k_gemm<2, true><<<GB, 256, 0, stream>>>(emb, aT0, S0, C0, xlb, xr, nullptr);
    k_agg<<<AGG_BLOCKS, 256, 0, stream>>>(rowptr, csr, xlb, xr, att, cbias, emb, out);        // h1

    // ---- layer 1 ----
    k_gemm<2, true><<<GB, 256, 0, stream>>>(out, aT1, S1, C1, xlb, xr, nullptr);
    k_agg<<<AGG_BLOCKS, 256, 0, stream>>>(rowptr, csr, xlb, xr, att + DD, cbias + DD, out, out); // h2

    // ---- final projection (MFMA, in-place per row tile) ----
    k_gemm<1, false><<<GB, 256, 0, stream>>>(out, fT, nullptr, Cf, nullptr, nullptr, out);
}

// Round 9
// 260.756 us; speedup vs baseline: 1.1353x; 1.1353x over previous
//
#include <hip/hip_runtime.h>
#include <math.h>

#define NN 100000      // nodes
#define DD 64          // dim
#define NE 1200000     // edges (without self-loops)
#define NB 391         // buckets of 256 nodes
#define SCH 2048       // edges per scatter block
#define GB ((NN + 63) / 64)   // 1563 row tiles for GEMM
#define HS 88          // LDS row stride in shorts (176B: 16B-aligned, <=2-way banks)

typedef __attribute__((ext_vector_type(8))) short bf16x8;
typedef __attribute__((ext_vector_type(4))) float f32x4;

__device__ __forceinline__ unsigned short f2bf(float x) {
    unsigned u = __float_as_uint(x);
    return (unsigned short)((u + 0x7FFFu + ((u >> 16) & 1u)) >> 16);   // RNE
}
__device__ __forceinline__ float bf2f(unsigned short b) {
    return __uint_as_float(((unsigned)b) << 16);
}

__device__ __forceinline__ float gelu_exact(float x) {
    return 0.5f * x * (1.0f + erff(x * 0.70710678118654752f));
}

__device__ __forceinline__ float leaky(float x) {
    return fmaxf(x, 0.f) + 0.2f * fminf(x, 0.f);
}

// ---------------- CSR build: two-level bucket sort (self-loops embedded) ----------------

__global__ __launch_bounds__(256) void k_bcount(const int* __restrict__ tgt, int* __restrict__ bcnt) {
    __shared__ int h[NB];
    for (int i = threadIdx.x; i < NB; i += 256) h[i] = 0;
    __syncthreads();
    const int stride = gridDim.x * 256;
    for (int i = blockIdx.x * 256 + threadIdx.x; i < NE; i += stride)
        atomicAdd(&h[tgt[i] >> 8], 1);
    __syncthreads();
    for (int i = threadIdx.x; i < NB; i += 256)
        if (h[i]) atomicAdd(&bcnt[i], h[i]);
}

__global__ __launch_bounds__(512) void k_bscan(const int* __restrict__ bcnt,
                                               int* __restrict__ bbase, int* __restrict__ wbase) {
    __shared__ int s[512];
    const int tid = threadIdx.x;
    const int v = (tid < NB) ? bcnt[tid] : 0;
    s[tid] = v;
    __syncthreads();
    for (int o = 1; o < 512; o <<= 1) {
        int t = (tid >= o) ? s[tid - o] : 0;
        __syncthreads();
        s[tid] += t;
        __syncthreads();
    }
    if (tid < NB) {
        int ex = s[tid] - v;
        bbase[tid] = ex;
        wbase[tid] = ex;
    }
    if (tid == NB - 1) bbase[NB] = s[tid];   // = NE
}

__global__ __launch_bounds__(256) void k_bscatter(const int* __restrict__ src, const int* __restrict__ tgt,
                                                  int* __restrict__ wbase, unsigned int* __restrict__ ebuf) {
    __shared__ int stgt[SCH];
    __shared__ unsigned short srk[SCH];
    __shared__ int hist[NB];
    __shared__ int hbase[NB];
    const int base = blockIdx.x * SCH;
    const int cnt = min(SCH, NE - base);
    const int tid = threadIdx.x;
    for (int i = tid; i < NB; i += 256) hist[i] = 0;
    for (int i = tid; i < cnt; i += 256) stgt[i] = tgt[base + i];
    __syncthreads();
    for (int i = tid; i < cnt; i += 256)
        srk[i] = (unsigned short)atomicAdd(&hist[stgt[i] >> 8], 1);
    __syncthreads();
    for (int b = tid; b < NB; b += 256) {
        int c = hist[b];
        hbase[b] = c ? atomicAdd(&wbase[b], c) : 0;
    }
    __syncthreads();
    for (int i = tid; i < cnt; i += 256) {
        int t = stgt[i];
        unsigned int e = ((unsigned int)src[base + i] << 8) | (unsigned int)(t & 255);
        ebuf[hbase[t >> 8] + (int)srk[i]] = e;
    }
}

__global__ __launch_bounds__(256) void k_bfinal(const int* __restrict__ bbase,
                                                const unsigned int* __restrict__ ebuf,
                                                int* __restrict__ rowptr, int* __restrict__ csr) {
    __shared__ int hist[256];
    __shared__ int pos[256];
    __shared__ int wsum[4];
    const int b = blockIdx.x, tid = threadIdx.x;
    const int bb = bbase[b], be = bbase[b + 1];
    hist[tid] = 0;
    __syncthreads();
    for (int i = bb + tid; i < be; i += 256) atomicAdd(&hist[ebuf[i] & 255u], 1);
    __syncthreads();
    const int v = hist[tid];
    const int lane = tid & 63, w = tid >> 6;
    int sc = v;
    #pragma unroll
    for (int o = 1; o < 64; o <<= 1) { int t = __shfl_up(sc, o, 64); if (lane >= o) sc += t; }
    if (lane == 63) wsum[w] = sc;
    __syncthreads();
    int off = 0;
    for (int k = 0; k < w; ++k) off += wsum[k];
    const int node = b * 256 + tid;
    const int rp = bb + off + sc - v + node;     // +node: one self slot per preceding node
    if (node < NN) {
        rowptr[node] = rp;
        csr[rp] = node;                          // self-loop first
    } else if (node == NN) {
        rowptr[NN] = rp;                         // = NE + NN
    }
    pos[tid] = rp + 1;                           // edges start after self
    __syncthreads();
    for (int i = bb + tid; i < be; i += 256) {
        unsigned int e = ebuf[i];
        int p = atomicAdd(&pos[e & 255u], 1);
        csr[p] = (int)(e >> 8);
    }
}

// ---------------- weight precompute: A = diag(g)W (bf16 hi/lo), S = g@W, C = beta@W ----------------
__global__ __launch_bounds__(128) void k_wprep(
    const float* __restrict__ Wl, const float* __restrict__ Wr,
    const float* __restrict__ g, const float* __restrict__ be,
    unsigned short* __restrict__ aT, float* __restrict__ S, float* __restrict__ C)
{
    const int c = threadIdx.x;          // 0..127
    const float* W = (c < 64) ? Wl : Wr;
    const int cc = c & 63;
    float s = 0.f, cC = 0.f;
    unsigned short* hi_p = aT + c * 64;
    unsigned short* lo_p = aT + 128 * 64 + c * 64;
    #pragma unroll 8
    for (int k = 0; k < 64; ++k) {
        float w = W[k * 64 + cc];
        float a = g[k] * w;
        unsigned short hi = f2bf(a);
        unsigned short lo = f2bf(a - bf2f(hi));
        hi_p[k] = hi; lo_p[k] = lo;
        s += a;
        cC = fmaf(be[k], w, cC);
    }
    S[c] = s; C[c] = cC;
}

__global__ __launch_bounds__(64) void k_wfinal(
    const float* __restrict__ pw, const float* __restrict__ pb,
    unsigned short* __restrict__ fT, float* __restrict__ Cf)
{
    const int c = threadIdx.x;  // 0..63
    unsigned short* hi_p = fT + c * 64;
    unsigned short* lo_p = fT + 64 * 64 + c * 64;
    #pragma unroll 8
    for (int k = 0; k < 64; ++k) {
        float w = pw[k * 64 + c];
        unsigned short hi = f2bf(w);
        unsigned short lo = f2bf(w - bf2f(hi));
        hi_p[k] = hi; lo_p[k] = lo;
    }
    Cf[c] = pb[c];
}

// ---------------- MFMA node GEMM ----------------
// LN=true: out = rho*(h@A) - rho*mean*S + C; cols<64 -> xlb (bf16), cols>=64 -> xr (fp32).
// LN=false: out = h@A + C -> outp fp32 (in-place safe per 64-row tile).
template<int CTW, bool LN>
__global__ __launch_bounds__(256) void k_gemm(
    const float* __restrict__ h, const unsigned short* __restrict__ aT,
    const float* __restrict__ S, const float* __restrict__ C,
    unsigned short* __restrict__ xlb, float* __restrict__ xr, float* __restrict__ outp)
{
    __shared__ __align__(16) unsigned short hbh[64 * HS];
    __shared__ __align__(16) unsigned short hbl[64 * HS];
    __shared__ float smean[64], srho[64];
    const int tid = threadIdx.x;
    const int tile = blockIdx.x * 64;
    {
        const int row = tid >> 2, q = tid & 3;
        const int node = min(tile + row, NN - 1);
        const float* hp = h + (size_t)node * DD + q * 16;
        float4 v[4];
        #pragma unroll
        for (int i = 0; i < 4; ++i) v[i] = *(const float4*)(hp + i * 4);
        if (LN) {
            float sum = 0.f, ssq = 0.f;
            #pragma unroll
            for (int i = 0; i < 4; ++i) {
                sum += v[i].x + v[i].y + v[i].z + v[i].w;
                ssq += v[i].x * v[i].x + v[i].y * v[i].y + v[i].z * v[i].z + v[i].w * v[i].w;
            }
            sum += __shfl_xor(sum, 1, 64); ssq += __shfl_xor(ssq, 1, 64);
            sum += __shfl_xor(sum, 2, 64); ssq += __shfl_xor(ssq, 2, 64);
            if (q == 0) {
                float mean = sum * 0.015625f;
                float var = ssq * 0.015625f - mean * mean;
                smean[row] = mean;
                srho[row] = rsqrtf(var + 1e-5f);
            }
        }
        #pragma unroll
        for (int half = 0; half < 2; ++half) {
            bf16x8 ph, pl;
            #pragma unroll
            for (int e = 0; e < 8; ++e) {
                float f = (&v[half * 2 + (e >> 2)].x)[e & 3];
                unsigned short hi = f2bf(f);
                unsigned short lo = f2bf(f - bf2f(hi));
                ph[e] = (short)hi; pl[e] = (short)lo;
            }
            const int so = row * HS + q * 16 + half * 8;
            *(bf16x8*)&hbh[so] = ph;
            *(bf16x8*)&hbl[so] = pl;
        }
    }
    __syncthreads();
    const int lane = tid & 63;
    const int wslot = tid >> 6;
    const int li16 = lane & 15;
    const int g16 = lane >> 4;
    const int NCT = CTW * 4;
    f32x4 acc[CTW][4];
    #pragma unroll
    for (int c = 0; c < CTW; ++c)
        #pragma unroll
        for (int rt = 0; rt < 4; ++rt) acc[c][rt] = (f32x4){0.f, 0.f, 0.f, 0.f};
    #pragma unroll
    for (int kk = 0; kk < 2; ++kk) {
        bf16x8 ah[4], al[4];
        #pragma unroll
        for (int rt = 0; rt < 4; ++rt) {
            const int so = (rt * 16 + li16) * HS + kk * 32 + g16 * 8;
            ah[rt] = *(const bf16x8*)&hbh[so];
            al[rt] = *(const bf16x8*)&hbl[so];
        }
        #pragma unroll
        for (int c = 0; c < CTW; ++c) {
            const int ct = wslot + c * 4;
            const unsigned short* bp = aT + (ct * 16 + li16) * 64 + kk * 32 + g16 * 8;
            bf16x8 bh = *(const bf16x8*)bp;
            bf16x8 bl = *(const bf16x8*)(bp + NCT * 16 * 64);
            #pragma unroll
            for (int rt = 0; rt < 4; ++rt) {
                acc[c][rt] = __builtin_amdgcn_mfma_f32_16x16x32_bf16(ah[rt], bh, acc[c][rt], 0, 0, 0);
                acc[c][rt] = __builtin_amdgcn_mfma_f32_16x16x32_bf16(al[rt], bh, acc[c][rt], 0, 0, 0);
                acc[c][rt] = __builtin_amdgcn_mfma_f32_16x16x32_bf16(ah[rt], bl, acc[c][rt], 0, 0, 0);
            }
        }
    }
    #pragma unroll
    for (int c = 0; c < CTW; ++c) {
        const int ct = wslot + c * 4;
        const int col = ct * 16 + li16;
        const float Cc = C[col];
        float Sc = 0.f;
        if (LN) Sc = S[col];
        #pragma unroll
        for (int rt = 0; rt < 4; ++rt) {
            const int r0 = rt * 16 + g16 * 4;
            #pragma unroll
            for (int j = 0; j < 4; ++j) {
                const int row2 = r0 + j;
                const int node = tile + row2;
                if (node < NN) {
                    float p = acc[c][rt][j];
                    if (LN) {
                        float val = fmaf(srho[row2], p - smean[row2] * Sc, Cc);
                        if (ct < 4) xlb[(size_t)node * DD + col]       = f2bf(val);
                        else        xr[(size_t)node * DD + (col & 63)] = val;
                    } else {
                        outp[(size_t)node * DD + col] = p + Cc;
                    }
                }
            }
        }
    }
}

// ---------------- aggregation: one wave per target node, 16 lanes x 4 edges, bf16 gather, 2-deep pipeline ----------------
__global__ __launch_bounds__(256) void k_agg(
    const int* __restrict__ rowptr, const int* __restrict__ csr,
    const unsigned short* __restrict__ xlb, const float* __restrict__ xr,
    const float* __restrict__ att, const float* __restrict__ cbias,
    const float* __restrict__ h_in, float* __restrict__ h_out)
{
    const int lane = threadIdx.x & 63;
    const int li   = lane & 15;     // feature-quad index
    const int sub  = lane >> 4;     // edge slot 0..3
    const int wid  = (blockIdx.x * 256 + threadIdx.x) >> 6;
    const int nw   = gridDim.x * 4;
    const float4 a4  = *(const float4*)&att[li * 4];
    const float4 cb4 = *(const float4*)&cbias[li * 4];
    for (int n = wid; n < NN; n += nw) {
        const float4 xrt = *(const float4*)&xr[(size_t)n * DD + li * 4];
        const int beg = rowptr[n], end = rowptr[n + 1];   // len >= 1 (self first)
        const int end1 = end - 1;
        // 2-deep software pipeline on the bf16 gather
        int j  = beg + sub;
        int jn = j + 4;
        int s0 = csr[min(j,  end1)];
        ushort4 v  = *(const ushort4*)&xlb[(size_t)s0 * DD + li * 4];
        int s1 = csr[min(jn, end1)];
        ushort4 vn = *(const ushort4*)&xlb[(size_t)s1 * DD + li * 4];
        float  den = 0.f;
        float4 acc = make_float4(0.f, 0.f, 0.f, 0.f);
        const int nch = (end - beg + 3) >> 2;
        for (int c = 0; c < nch; ++c) {
            const ushort4 cur = v;
            const int jcur = j;
            v = vn;
            j = jn;
            jn += 4;
            int s2 = csr[min(jn, end1)];
            vn = *(const ushort4*)&xlb[(size_t)s2 * DD + li * 4];   // prefetch c+2 (clamped)
            float f0 = bf2f(cur.x), f1 = bf2f(cur.y), f2 = bf2f(cur.z), f3 = bf2f(cur.w);
            float p = leaky(f0 + xrt.x) * a4.x;
            p = fmaf(leaky(f1 + xrt.y), a4.y, p);
            p = fmaf(leaky(f2 + xrt.z), a4.z, p);
            p = fmaf(leaky(f3 + xrt.w), a4.w, p);
            p += __shfl_xor(p, 1, 64);
            p += __shfl_xor(p, 2, 64);
            p += __shfl_xor(p, 4, 64);
            p += __shfl_xor(p, 8, 64);
            float ex = (jcur < end) ? __expf(p) : 0.f;
            den += ex;
            acc.x = fmaf(ex, f0, acc.x);
            acc.y = fmaf(ex, f1, acc.y);
            acc.z = fmaf(ex, f2, acc.z);
            acc.w = fmaf(ex, f3, acc.w);
        }
        #pragma unroll
        for (int o = 16; o < 64; o <<= 1) {
            acc.x += __shfl_xor(acc.x, o, 64);
            acc.y += __shfl_xor(acc.y, o, 64);
            acc.z += __shfl_xor(acc.z, o, 64);
            acc.w += __shfl_xor(acc.w, o, 64);
            den   += __shfl_xor(den,   o, 64);
        }
        if (sub == 0) {
            const float id = 1.f / (den + 1e-16f);
            const float4 hi = *(const float4*)&h_in[(size_t)n * DD + li * 4];
            float4 o4;
            o4.x = gelu_exact(fmaf(acc.x, id, cb4.x)) + hi.x;
            o4.y = gelu_exact(fmaf(acc.y, id, cb4.y)) + hi.y;
            o4.z = gelu_exact(fmaf(acc.z, id, cb4.z)) + hi.z;
            o4.w = gelu_exact(fmaf(acc.w, id, cb4.w)) + hi.w;
            *(float4*)&h_out[(size_t)n * DD + li * 4] = o4;
        }
    }
}

extern "C" void kernel_launch(void* const* d_in, const int* in_sizes, int n_in,
                              void* d_out, int out_size, void* d_ws, size_t ws_size,
                              hipStream_t stream) {
    const int*   edge_index = (const int*)d_in[1];
    const int*   src   = edge_index;
    const int*   tgt   = edge_index + NE;
    const float* emb   = (const float*)d_in[2];
    const float* ln_g  = (const float*)d_in[3];
    const float* ln_b  = (const float*)d_in[4];
    const float* Wl    = (const float*)d_in[5];
    const float* Wr    = (const float*)d_in[6];
    const float* att   = (const float*)d_in[7];
    const float* cbias = (const float*)d_in[8];
    const float* pw    = (const float*)d_in[9];
    const float* pb    = (const float*)d_in[10];
    float* out = (float*)d_out;

    unsigned short* xlb = (unsigned short*)d_ws;           // NN*64 bf16
    float* xr = (float*)(xlb + (size_t)NN * DD);
    int* csr             = (int*)(xr + (size_t)NN * DD);   // NE+NN
    unsigned int* ebuf   = (unsigned int*)(csr + NE + NN);
    int* rowptr          = (int*)(ebuf + NE);              // NN+8
    int* bcnt            = rowptr + NN + 8;                // 392 (padded)
    int* bbase           = bcnt + 392;                     // 400 (padded)
    int* wbase           = bbase + 400;                    // 400 (padded)
    unsigned short* aT0  = (unsigned short*)(wbase + 400); // 2*128*64
    unsigned short* aT1  = aT0 + 2 * 128 * 64;
    unsigned short* fT   = aT1 + 2 * 128 * 64;             // 2*64*64
    float* S0 = (float*)(fT + 2 * 64 * 64);
    float* C0 = S0 + 128;
    float* S1 = C0 + 128;
    float* C1 = S1 + 128;
    float* Cf = C1 + 128;

    const int AGG_BLOCKS = 2048;

    // ---- weight precompute (tiny) ----
    k_wprep<<<1, 128, 0, stream>>>(Wl, Wr, ln_g, ln_b, aT0, S0, C0);
    k_wprep<<<1, 128, 0, stream>>>(Wl + DD * DD, Wr + DD * DD, ln_g + DD, ln_b + DD, aT1, S1, C1);
    k_wfinal<<<1, 64, 0, stream>>>(pw, pb, fT, Cf);

    // ---- CSR build (two-level bucket sort by target, self-loops embedded) ----
    hipMemsetAsync(bcnt, 0, NB * sizeof(int), stream);
    k_bcount<<<256, 256, 0, stream>>>(tgt, bcnt);
    k_bscan<<<1, 512, 0, stream>>>(bcnt, bbase, wbase);
    k_bscatter<<<(NE + SCH - 1) / SCH, 256, 0, stream>>>(src, tgt, wbase, ebuf);
    k_bfinal<<<NB, 256, 0, stream>>>(bbase, ebuf, rowptr, csr);

    // ---- layer 0 ----
    k_gemm<2, true><<<GB, 256, 0, stream>>>(emb, aT0, S0, C0, xlb, xr, nullptr);
    k_agg<<<AGG_BLOCKS, 256, 0, stream>>>(rowptr, csr, xlb, xr, att, cbias, emb, out);        // h1

    // ---- layer 1 ----
    k_gemm<2, true><<<GB, 256, 0, stream>>>(out, aT1, S1, C1, xlb, xr, nullptr);
    k_agg<<<AGG_BLOCKS, 256, 0, stream>>>(rowptr, csr, xlb, xr, att + DD, cbias + DD, out, out); // h2

    // ---- final projection (MFMA, in-place per row tile) ----
    k_gemm<1, false><<<GB, 256, 0, stream>>>(out, fT, nullptr, Cf, nullptr, nullptr, out);
}

// Round 10
// 242.854 us; speedup vs baseline: 1.2190x; 1.0737x over previous
//
#include <hip/hip_runtime.h>
#include <math.h>

#define NN 100000      // nodes
#define DD 64          // dim
#define NE 1200000     // edges (without self-loops)
#define NB 391         // buckets of 256 nodes
#define SCH 2048       // edges per scatter block
#define GB ((NN + 63) / 64)   // 1563 row tiles for GEMM
#define HS 88          // LDS row stride in shorts (176B: 16B-aligned, <=2-way banks)

typedef __attribute__((ext_vector_type(8))) short bf16x8;
typedef __attribute__((ext_vector_type(4))) float f32x4;

__device__ __forceinline__ unsigned short f2bf(float x) {
    unsigned u = __float_as_uint(x);
    return (unsigned short)((u + 0x7FFFu + ((u >> 16) & 1u)) >> 16);   // RNE
}
__device__ __forceinline__ float bf2f(unsigned short b) {
    return __uint_as_float(((unsigned)b) << 16);
}

__device__ __forceinline__ float gelu_exact(float x) {
    return 0.5f * x * (1.0f + erff(x * 0.70710678118654752f));
}

// sum across each 16-lane row via DPP row_ror 1/2/4/8 (pure VALU, no DS)
__device__ __forceinline__ float row16_sum(float x) {
    int t;
    t = __builtin_amdgcn_update_dpp(0, __float_as_int(x), 0x121, 0xf, 0xf, true);
    x += __int_as_float(t);
    t = __builtin_amdgcn_update_dpp(0, __float_as_int(x), 0x122, 0xf, 0xf, true);
    x += __int_as_float(t);
    t = __builtin_amdgcn_update_dpp(0, __float_as_int(x), 0x124, 0xf, 0xf, true);
    x += __int_as_float(t);
    t = __builtin_amdgcn_update_dpp(0, __float_as_int(x), 0x128, 0xf, 0xf, true);
    x += __int_as_float(t);
    return x;
}

// ---------------- CSR build: two-level bucket sort (self-loops embedded) ----------------

__global__ __launch_bounds__(256) void k_bcount(const int* __restrict__ tgt, int* __restrict__ bcnt) {
    __shared__ int h[NB];
    for (int i = threadIdx.x; i < NB; i += 256) h[i] = 0;
    __syncthreads();
    const int stride = gridDim.x * 256;
    for (int i = blockIdx.x * 256 + threadIdx.x; i < NE; i += stride)
        atomicAdd(&h[tgt[i] >> 8], 1);
    __syncthreads();
    for (int i = threadIdx.x; i < NB; i += 256)
        if (h[i]) atomicAdd(&bcnt[i], h[i]);
}

__global__ __launch_bounds__(512) void k_bscan(const int* __restrict__ bcnt,
                                               int* __restrict__ bbase, int* __restrict__ wbase) {
    __shared__ int s[512];
    const int tid = threadIdx.x;
    const int v = (tid < NB) ? bcnt[tid] : 0;
    s[tid] = v;
    __syncthreads();
    for (int o = 1; o < 512; o <<= 1) {
        int t = (tid >= o) ? s[tid - o] : 0;
        __syncthreads();
        s[tid] += t;
        __syncthreads();
    }
    if (tid < NB) {
        int ex = s[tid] - v;
        bbase[tid] = ex;
        wbase[tid] = ex;
    }
    if (tid == NB - 1) bbase[NB] = s[tid];   // = NE
}

__global__ __launch_bounds__(256) void k_bscatter(const int* __restrict__ src, const int* __restrict__ tgt,
                                                  int* __restrict__ wbase, unsigned int* __restrict__ ebuf) {
    __shared__ int stgt[SCH];
    __shared__ unsigned short srk[SCH];
    __shared__ int hist[NB];
    __shared__ int hbase[NB];
    const int base = blockIdx.x * SCH;
    const int cnt = min(SCH, NE - base);
    const int tid = threadIdx.x;
    for (int i = tid; i < NB; i += 256) hist[i] = 0;
    for (int i = tid; i < cnt; i += 256) stgt[i] = tgt[base + i];
    __syncthreads();
    for (int i = tid; i < cnt; i += 256)
        srk[i] = (unsigned short)atomicAdd(&hist[stgt[i] >> 8], 1);
    __syncthreads();
    for (int b = tid; b < NB; b += 256) {
        int c = hist[b];
        hbase[b] = c ? atomicAdd(&wbase[b], c) : 0;
    }
    __syncthreads();
    for (int i = tid; i < cnt; i += 256) {
        int t = stgt[i];
        unsigned int e = ((unsigned int)src[base + i] << 8) | (unsigned int)(t & 255);
        ebuf[hbase[t >> 8] + (int)srk[i]] = e;
    }
}

__global__ __launch_bounds__(256) void k_bfinal(const int* __restrict__ bbase,
                                                const unsigned int* __restrict__ ebuf,
                                                int* __restrict__ rowptr, int* __restrict__ csr) {
    __shared__ int hist[256];
    __shared__ int pos[256];
    __shared__ int wsum[4];
    const int b = blockIdx.x, tid = threadIdx.x;
    const int bb = bbase[b], be = bbase[b + 1];
    hist[tid] = 0;
    __syncthreads();
    for (int i = bb + tid; i < be; i += 256) atomicAdd(&hist[ebuf[i] & 255u], 1);
    __syncthreads();
    const int v = hist[tid];
    const int lane = tid & 63, w = tid >> 6;
    int sc = v;
    #pragma unroll
    for (int o = 1; o < 64; o <<= 1) { int t = __shfl_up(sc, o, 64); if (lane >= o) sc += t; }
    if (lane == 63) wsum[w] = sc;
    __syncthreads();
    int off = 0;
    for (int k = 0; k < w; ++k) off += wsum[k];
    const int node = b * 256 + tid;
    const int rp = bb + off + sc - v + node;     // +node: one self slot per preceding node
    if (node < NN) {
        rowptr[node] = rp;
        csr[rp] = node;                          // self-loop first
    } else if (node == NN) {
        rowptr[NN] = rp;                         // = NE + NN
    }
    pos[tid] = rp + 1;                           // edges start after self
    __syncthreads();
    for (int i = bb + tid; i < be; i += 256) {
        unsigned int e = ebuf[i];
        int p = atomicAdd(&pos[e & 255u], 1);
        csr[p] = (int)(e >> 8);
    }
}

// ---------------- fused weight precompute + bcnt zero (one dispatch) ----------------
// block 0: layer0 A=diag(g)W hi/lo, S, C.  block 1: layer1.  block 2: post_w hi/lo + pb, zero bcnt.
__global__ __launch_bounds__(128) void k_wall(
    const float* __restrict__ Wl, const float* __restrict__ Wr,
    const float* __restrict__ g, const float* __restrict__ be,
    const float* __restrict__ pw, const float* __restrict__ pb,
    unsigned short* __restrict__ aT0, unsigned short* __restrict__ aT1,
    unsigned short* __restrict__ fT,
    float* __restrict__ S0, float* __restrict__ C0,
    float* __restrict__ S1, float* __restrict__ C1, float* __restrict__ Cf,
    int* __restrict__ bcnt)
{
    const int blk = blockIdx.x;
    const int c = threadIdx.x;          // 0..127
    if (blk < 2) {
        const float* WL = Wl + blk * DD * DD;
        const float* WR = Wr + blk * DD * DD;
        const float* gg = g + blk * DD;
        const float* bb = be + blk * DD;
        unsigned short* aT = blk ? aT1 : aT0;
        float* S = blk ? S1 : S0;
        float* C = blk ? C1 : C0;
        const float* W = (c < 64) ? WL : WR;
        const int cc = c & 63;
        float s = 0.f, cC = 0.f;
        unsigned short* hi_p = aT + c * 64;
        unsigned short* lo_p = aT + 128 * 64 + c * 64;
        #pragma unroll 8
        for (int k = 0; k < 64; ++k) {
            float w = W[k * 64 + cc];
            float a = gg[k] * w;
            unsigned short hi = f2bf(a);
            unsigned short lo = f2bf(a - bf2f(hi));
            hi_p[k] = hi; lo_p[k] = lo;
            s += a;
            cC = fmaf(bb[k], w, cC);
        }
        S[c] = s; C[c] = cC;
    } else {
        if (c < 64) {
            unsigned short* hi_p = fT + c * 64;
            unsigned short* lo_p = fT + 64 * 64 + c * 64;
            #pragma unroll 8
            for (int k = 0; k < 64; ++k) {
                float w = pw[k * 64 + c];
                unsigned short hi = f2bf(w);
                unsigned short lo = f2bf(w - bf2f(hi));
                hi_p[k] = hi; lo_p[k] = lo;
            }
            Cf[c] = pb[c];
        } else {
            for (int i = c - 64; i < NB; i += 64) bcnt[i] = 0;
        }
    }
}

// ---------------- MFMA node GEMM ----------------
// LN=true: out = rho*(h@A) - rho*mean*S + C; cols<64 -> xlb (bf16), cols>=64 -> xr (fp32).
// LN=false: out = h@A + C -> outp fp32 (in-place safe per 64-row tile).
template<int CTW, bool LN>
__global__ __launch_bounds__(256) void k_gemm(
    const float* __restrict__ h, const unsigned short* __restrict__ aT,
    const float* __restrict__ S, const float* __restrict__ C,
    unsigned short* __restrict__ xlb, float* __restrict__ xr, float* __restrict__ outp)
{
    __shared__ __align__(16) unsigned short hbh[64 * HS];
    __shared__ __align__(16) unsigned short hbl[64 * HS];
    __shared__ float smean[64], srho[64];
    const int tid = threadIdx.x;
    const int tile = blockIdx.x * 64;
    {
        const int row = tid >> 2, q = tid & 3;
        const int node = min(tile + row, NN - 1);
        const float* hp = h + (size_t)node * DD + q * 16;
        float4 v[4];
        #pragma unroll
        for (int i = 0; i < 4; ++i) v[i] = *(const float4*)(hp + i * 4);
        if (LN) {
            float sum = 0.f, ssq = 0.f;
            #pragma unroll
            for (int i = 0; i < 4; ++i) {
                sum += v[i].x + v[i].y + v[i].z + v[i].w;
                ssq += v[i].x * v[i].x + v[i].y * v[i].y + v[i].z * v[i].z + v[i].w * v[i].w;
            }
            sum += __shfl_xor(sum, 1, 64); ssq += __shfl_xor(ssq, 1, 64);
            sum += __shfl_xor(sum, 2, 64); ssq += __shfl_xor(ssq, 2, 64);
            if (q == 0) {
                float mean = sum * 0.015625f;
                float var = ssq * 0.015625f - mean * mean;
                smean[row] = mean;
                srho[row] = rsqrtf(var + 1e-5f);
            }
        }
        #pragma unroll
        for (int half = 0; half < 2; ++half) {
            bf16x8 ph, pl;
            #pragma unroll
            for (int e = 0; e < 8; ++e) {
                float f = (&v[half * 2 + (e >> 2)].x)[e & 3];
                unsigned short hi = f2bf(f);
                unsigned short lo = f2bf(f - bf2f(hi));
                ph[e] = (short)hi; pl[e] = (short)lo;
            }
            const int so = row * HS + q * 16 + half * 8;
            *(bf16x8*)&hbh[so] = ph;
            *(bf16x8*)&hbl[so] = pl;
        }
    }
    __syncthreads();
    const int lane = tid & 63;
    const int wslot = tid >> 6;
    const int li16 = lane & 15;
    const int g16 = lane >> 4;
    const int NCT = CTW * 4;
    f32x4 acc[CTW][4];
    #pragma unroll
    for (int c = 0; c < CTW; ++c)
        #pragma unroll
        for (int rt = 0; rt < 4; ++rt) acc[c][rt] = (f32x4){0.f, 0.f, 0.f, 0.f};
    #pragma unroll
    for (int kk = 0; kk < 2; ++kk) {
        bf16x8 ah[4], al[4];
        #pragma unroll
        for (int rt = 0; rt < 4; ++rt) {
            const int so = (rt * 16 + li16) * HS + kk * 32 + g16 * 8;
            ah[rt] = *(const bf16x8*)&hbh[so];
            al[rt] = *(const bf16x8*)&hbl[so];
        }
        #pragma unroll
        for (int c = 0; c < CTW; ++c) {
            const int ct = wslot + c * 4;
            const unsigned short* bp = aT + (ct * 16 + li16) * 64 + kk * 32 + g16 * 8;
            bf16x8 bh = *(const bf16x8*)bp;
            bf16x8 bl = *(const bf16x8*)(bp + NCT * 16 * 64);
            #pragma unroll
            for (int rt = 0; rt < 4; ++rt) {
                acc[c][rt] = __builtin_amdgcn_mfma_f32_16x16x32_bf16(ah[rt], bh, acc[c][rt], 0, 0, 0);
                acc[c][rt] = __builtin_amdgcn_mfma_f32_16x16x32_bf16(al[rt], bh, acc[c][rt], 0, 0, 0);
                acc[c][rt] = __builtin_amdgcn_mfma_f32_16x16x32_bf16(ah[rt], bl, acc[c][rt], 0, 0, 0);
            }
        }
    }
    #pragma unroll
    for (int c = 0; c < CTW; ++c) {
        const int ct = wslot + c * 4;
        const int col = ct * 16 + li16;
        const float Cc = C[col];
        float Sc = 0.f;
        if (LN) Sc = S[col];
        #pragma unroll
        for (int rt = 0; rt < 4; ++rt) {
            const int r0 = rt * 16 + g16 * 4;
            #pragma unroll
            for (int j = 0; j < 4; ++j) {
                const int row2 = r0 + j;
                const int node = tile + row2;
                if (node < NN) {
                    float p = acc[c][rt][j];
                    if (LN) {
                        float val = fmaf(srho[row2], p - smean[row2] * Sc, Cc);
                        if (ct < 4) xlb[(size_t)node * DD + col]       = f2bf(val);
                        else        xr[(size_t)node * DD + (col & 63)] = val;
                    } else {
                        outp[(size_t)node * DD + col] = p + Cc;
                    }
                }
            }
        }
    }
}

// ---------------- aggregation: one wave per target node, 16 lanes x 4 edges ----------------
// bf16 gather, 2-deep pipeline, DPP reduce, leaky via |t| modifier, exp2-domain logits.
__global__ __launch_bounds__(256) void k_agg(
    const int* __restrict__ rowptr, const int* __restrict__ csr,
    const unsigned short* __restrict__ xlb, const float* __restrict__ xr,
    const float* __restrict__ att, const float* __restrict__ cbias,
    const float* __restrict__ h_in, float* __restrict__ h_out)
{
    const int lane = threadIdx.x & 63;
    const int li   = lane & 15;     // feature-quad index
    const int sub  = lane >> 4;     // edge slot 0..3
    const int li4  = li * 4;
    const int wid  = (blockIdx.x * 256 + threadIdx.x) >> 6;
    const int nw   = gridDim.x * 4;
    const float L2E = 1.4426950408889634f;
    const float4 ar = *(const float4*)&att[li4];
    // leaky(t)*a = (0.6a)t + (0.4a)|t|; log2e folded for exp2-domain softmax
    const float4 a06 = make_float4(0.6f*L2E*ar.x, 0.6f*L2E*ar.y, 0.6f*L2E*ar.z, 0.6f*L2E*ar.w);
    const float4 a04 = make_float4(0.4f*L2E*ar.x, 0.4f*L2E*ar.y, 0.4f*L2E*ar.z, 0.4f*L2E*ar.w);
    const float4 cb4 = *(const float4*)&cbias[li4];
    for (int n = wid; n < NN; n += nw) {
        const float4 xrt = *(const float4*)&xr[(size_t)n * DD + li4];
        const int beg = rowptr[n], end = rowptr[n + 1];   // len >= 1 (self first)
        const int end1 = end - 1;
        // 2-deep software pipeline on the bf16 gather (32-bit offsets)
        int j  = beg + sub;
        int jn = j + 4;
        unsigned o0 = ((unsigned)csr[min(j,  end1)] << 6) + li4;
        ushort4 v  = *(const ushort4*)&xlb[o0];
        unsigned o1 = ((unsigned)csr[min(jn, end1)] << 6) + li4;
        ushort4 vn = *(const ushort4*)&xlb[o1];
        float  den = 0.f;
        float4 acc = make_float4(0.f, 0.f, 0.f, 0.f);
        const int nch = (end - beg + 3) >> 2;
        for (int c = 0; c < nch; ++c) {
            const ushort4 cur = v;
            const int jcur = j;
            v = vn;
            j = jn;
            jn += 4;
            unsigned o2 = ((unsigned)csr[min(jn, end1)] << 6) + li4;
            vn = *(const ushort4*)&xlb[o2];                    // prefetch c+2 (clamped)
            float f0 = bf2f(cur.x), f1 = bf2f(cur.y), f2 = bf2f(cur.z), f3 = bf2f(cur.w);
            float t0 = f0 + xrt.x, t1 = f1 + xrt.y, t2 = f2 + xrt.z, t3 = f3 + xrt.w;
            float p = t0 * a06.x;
            float q = fabsf(t0) * a04.x;
            p = fmaf(t1, a06.y, p);  q = fmaf(fabsf(t1), a04.y, q);
            p = fmaf(t2, a06.z, p);  q = fmaf(fabsf(t2), a04.z, q);
            p = fmaf(t3, a06.w, p);  q = fmaf(fabsf(t3), a04.w, q);
            p = row16_sum(p + q);
            float ex = (jcur < end) ? exp2f(p) : 0.f;
            den += ex;
            acc.x = fmaf(ex, f0, acc.x);
            acc.y = fmaf(ex, f1, acc.y);
            acc.z = fmaf(ex, f2, acc.z);
            acc.w = fmaf(ex, f3, acc.w);
        }
        #pragma unroll
        for (int o = 16; o < 64; o <<= 1) {
            acc.x += __shfl_xor(acc.x, o, 64);
            acc.y += __shfl_xor(acc.y, o, 64);
            acc.z += __shfl_xor(acc.z, o, 64);
            acc.w += __shfl_xor(acc.w, o, 64);
            den   += __shfl_xor(den,   o, 64);
        }
        if (sub == 0) {
            const float id = 1.f / (den + 1e-16f);
            const float4 hi = *(const float4*)&h_in[(size_t)n * DD + li4];
            float4 o4;
            o4.x = gelu_exact(fmaf(acc.x, id, cb4.x)) + hi.x;
            o4.y = gelu_exact(fmaf(acc.y, id, cb4.y)) + hi.y;
            o4.z = gelu_exact(fmaf(acc.z, id, cb4.z)) + hi.z;
            o4.w = gelu_exact(fmaf(acc.w, id, cb4.w)) + hi.w;
            *(float4*)&h_out[(size_t)n * DD + li4] = o4;
        }
    }
}

extern "C" void kernel_launch(void* const* d_in, const int* in_sizes, int n_in,
                              void* d_out, int out_size, void* d_ws, size_t ws_size,
                              hipStream_t stream) {
    const int*   edge_index = (const int*)d_in[1];
    const int*   src   = edge_index;
    const int*   tgt   = edge_index + NE;
    const float* emb   = (const float*)d_in[2];
    const float* ln_g  = (const float*)d_in[3];
    const float* ln_b  = (const float*)d_in[4];
    const float* Wl    = (const float*)d_in[5];
    const float* Wr    = (const float*)d_in[6];
    const float* att   = (const float*)d_in[7];
    const float* cbias = (const float*)d_in[8];
    const float* pw    = (const float*)d_in[9];
    const float* pb    = (const float*)d_in[10];
    float* out = (float*)d_out;

    unsigned short* xlb = (unsigned short*)d_ws;           // NN*64 bf16
    float* xr = (float*)(xlb + (size_t)NN * DD);
    int* csr             = (int*)(xr + (size_t)NN * DD);   // NE+NN
    unsigned int* ebuf   = (unsigned int*)(csr + NE + NN);
    int* rowptr          = (int*)(ebuf + NE);              // NN+8
    int* bcnt            = rowptr + NN + 8;                // 392 (padded)
    int* bbase           = bcnt + 392;                     // 400 (padded)
    int* wbase           = bbase + 400;                    // 400 (padded)
    unsigned short* aT0  = (unsigned short*)(wbase + 400); // 2*128*64
    unsigned short* aT1  = aT0 + 2 * 128 * 64;
    unsigned short* fT   = aT1 + 2 * 128 * 64;             // 2*64*64
    float* S0 = (float*)(fT + 2 * 64 * 64);
    float* C0 = S0 + 128;
    float* S1 = C0 + 128;
    float* C1 = S1 + 128;
    float* Cf = C1 + 128;

    const int AGG_BLOCKS = 2048;

    // ---- fused weight precompute + bcnt zero ----
    k_wall<<<3, 128, 0, stream>>>(Wl, Wr, ln_g, ln_b, pw, pb,
                                  aT0, aT1, fT, S0, C0, S1, C1, Cf, bcnt);

    // ---- CSR build (two-level bucket sort by target, self-loops embedded) ----
    k_bcount<<<256, 256, 0, stream>>>(tgt, bcnt);
    k_bscan<<<1, 512, 0, stream>>>(bcnt, bbase, wbase);
    k_bscatter<<<(NE + SCH - 1) / SCH, 256, 0, stream>>>(src, tgt, wbase, ebuf);
    k_bfinal<<<NB, 256, 0, stream>>>(bbase, ebuf, rowptr, csr);

    // ---- layer 0 ----
    k_gemm<2, true><<<GB, 256, 0, stream>>>(emb, aT0, S0, C0, xlb, xr, nullptr);
    k_agg<<<AGG_BLOCKS, 256, 0, stream>>>(rowptr, csr, xlb, xr, att, cbias, emb, out);        // h1

    // ---- layer 1 ----
    k_gemm<2, true><<<GB, 256, 0, stream>>>(out, aT1, S1, C1, xlb, xr, nullptr);
    k_agg<<<AGG_BLOCKS, 256, 0, stream>>>(rowptr, csr, xlb, xr, att + DD, cbias + DD, out, out); // h2

    // ---- final projection (MFMA, in-place per row tile) ----
    k_gemm<1, false><<<GB, 256, 0, stream>>>(out, fT, nullptr, Cf, nullptr, nullptr, out);
}

// Round 11
// 241.883 us; speedup vs baseline: 1.2239x; 1.0040x over previous
//
#include <hip/hip_runtime.h>
#include <math.h>

#define NN 100000      // nodes
#define DD 64          // dim
#define NE 1200000     // edges (without self-loops)
#define NB 391         // buckets of 256 nodes
#define SCH 2048       // edges per scatter block
#define GB ((NN + 63) / 64)   // 1563 row tiles for GEMM
#define HS 88          // LDS row stride in shorts (176B: 16B-aligned, <=2-way banks)

typedef __attribute__((ext_vector_type(8))) short bf16x8;
typedef __attribute__((ext_vector_type(4))) float f32x4;
typedef __attribute__((ext_vector_type(2))) float f32x2;

#if __has_builtin(__builtin_amdgcn_exp2f)
#define EXP2(x) __builtin_amdgcn_exp2f(x)
#else
#define EXP2(x) exp2f(x)
#endif

__device__ __forceinline__ unsigned short f2bf(float x) {
    unsigned u = __float_as_uint(x);
    return (unsigned short)((u + 0x7FFFu + ((u >> 16) & 1u)) >> 16);   // RNE
}
__device__ __forceinline__ float bf2f(unsigned short b) {
    return __uint_as_float(((unsigned)b) << 16);
}

__device__ __forceinline__ float gelu_exact(float x) {
    return 0.5f * x * (1.0f + erff(x * 0.70710678118654752f));
}

// sum across each 16-lane row via DPP row_ror 1/2/4/8 (pure VALU, no DS)
__device__ __forceinline__ float row16_sum(float x) {
    int t;
    t = __builtin_amdgcn_update_dpp(0, __float_as_int(x), 0x121, 0xf, 0xf, true);
    x += __int_as_float(t);
    t = __builtin_amdgcn_update_dpp(0, __float_as_int(x), 0x122, 0xf, 0xf, true);
    x += __int_as_float(t);
    t = __builtin_amdgcn_update_dpp(0, __float_as_int(x), 0x124, 0xf, 0xf, true);
    x += __int_as_float(t);
    t = __builtin_amdgcn_update_dpp(0, __float_as_int(x), 0x128, 0xf, 0xf, true);
    x += __int_as_float(t);
    return x;
}

// ---------------- CSR build: two-level bucket sort (self-loops embedded) ----------------

__global__ __launch_bounds__(256) void k_bcount(const int* __restrict__ tgt, int* __restrict__ bcnt) {
    __shared__ int h[NB];
    for (int i = threadIdx.x; i < NB; i += 256) h[i] = 0;
    __syncthreads();
    const int stride = gridDim.x * 256;
    for (int i = blockIdx.x * 256 + threadIdx.x; i < NE; i += stride)
        atomicAdd(&h[tgt[i] >> 8], 1);
    __syncthreads();
    for (int i = threadIdx.x; i < NB; i += 256)
        if (h[i]) atomicAdd(&bcnt[i], h[i]);
}

__global__ __launch_bounds__(512) void k_bscan(const int* __restrict__ bcnt,
                                               int* __restrict__ bbase, int* __restrict__ wbase) {
    __shared__ int s[512];
    const int tid = threadIdx.x;
    const int v = (tid < NB) ? bcnt[tid] : 0;
    s[tid] = v;
    __syncthreads();
    for (int o = 1; o < 512; o <<= 1) {
        int t = (tid >= o) ? s[tid - o] : 0;
        __syncthreads();
        s[tid] += t;
        __syncthreads();
    }
    if (tid < NB) {
        int ex = s[tid] - v;
        bbase[tid] = ex;
        wbase[tid] = ex;
    }
    if (tid == NB - 1) bbase[NB] = s[tid];   // = NE
}

__global__ __launch_bounds__(256) void k_bscatter(const int* __restrict__ src, const int* __restrict__ tgt,
                                                  int* __restrict__ wbase, unsigned int* __restrict__ ebuf) {
    __shared__ int stgt[SCH];
    __shared__ unsigned short srk[SCH];
    __shared__ int hist[NB];
    __shared__ int hbase[NB];
    const int base = blockIdx.x * SCH;
    const int cnt = min(SCH, NE - base);
    const int tid = threadIdx.x;
    for (int i = tid; i < NB; i += 256) hist[i] = 0;
    for (int i = tid; i < cnt; i += 256) stgt[i] = tgt[base + i];
    __syncthreads();
    for (int i = tid; i < cnt; i += 256)
        srk[i] = (unsigned short)atomicAdd(&hist[stgt[i] >> 8], 1);
    __syncthreads();
    for (int b = tid; b < NB; b += 256) {
        int c = hist[b];
        hbase[b] = c ? atomicAdd(&wbase[b], c) : 0;
    }
    __syncthreads();
    for (int i = tid; i < cnt; i += 256) {
        int t = stgt[i];
        unsigned int e = ((unsigned int)src[base + i] << 8) | (unsigned int)(t & 255);
        ebuf[hbase[t >> 8] + (int)srk[i]] = e;
    }
}

__global__ __launch_bounds__(256) void k_bfinal(const int* __restrict__ bbase,
                                                const unsigned int* __restrict__ ebuf,
                                                int* __restrict__ rowptr, int* __restrict__ csr) {
    __shared__ int hist[256];
    __shared__ int pos[256];
    __shared__ int wsum[4];
    const int b = blockIdx.x, tid = threadIdx.x;
    const int bb = bbase[b], be = bbase[b + 1];
    hist[tid] = 0;
    __syncthreads();
    for (int i = bb + tid; i < be; i += 256) atomicAdd(&hist[ebuf[i] & 255u], 1);
    __syncthreads();
    const int v = hist[tid];
    const int lane = tid & 63, w = tid >> 6;
    int sc = v;
    #pragma unroll
    for (int o = 1; o < 64; o <<= 1) { int t = __shfl_up(sc, o, 64); if (lane >= o) sc += t; }
    if (lane == 63) wsum[w] = sc;
    __syncthreads();
    int off = 0;
    for (int k = 0; k < w; ++k) off += wsum[k];
    const int node = b * 256 + tid;
    const int rp = bb + off + sc - v + node;     // +node: one self slot per preceding node
    if (node < NN) {
        rowptr[node] = rp;
        csr[rp] = node << 6;                     // self-loop first (pre-scaled by DD)
    } else if (node == NN) {
        rowptr[NN] = rp;                         // = NE + NN
    }
    pos[tid] = rp + 1;                           // edges start after self
    __syncthreads();
    for (int i = bb + tid; i < be; i += 256) {
        unsigned int e = ebuf[i];
        int p = atomicAdd(&pos[e & 255u], 1);
        csr[p] = (int)(e >> 8) << 6;             // pre-scaled by DD
    }
}

// ---------------- fused weight precompute + bcnt zero (one dispatch) ----------------
__global__ __launch_bounds__(128) void k_wall(
    const float* __restrict__ Wl, const float* __restrict__ Wr,
    const float* __restrict__ g, const float* __restrict__ be,
    const float* __restrict__ pw, const float* __restrict__ pb,
    unsigned short* __restrict__ aT0, unsigned short* __restrict__ aT1,
    unsigned short* __restrict__ fT,
    float* __restrict__ S0, float* __restrict__ C0,
    float* __restrict__ S1, float* __restrict__ C1, float* __restrict__ Cf,
    int* __restrict__ bcnt)
{
    const int blk = blockIdx.x;
    const int c = threadIdx.x;          // 0..127
    if (blk < 2) {
        const float* WL = Wl + blk * DD * DD;
        const float* WR = Wr + blk * DD * DD;
        const float* gg = g + blk * DD;
        const float* bb = be + blk * DD;
        unsigned short* aT = blk ? aT1 : aT0;
        float* S = blk ? S1 : S0;
        float* C = blk ? C1 : C0;
        const float* W = (c < 64) ? WL : WR;
        const int cc = c & 63;
        float s = 0.f, cC = 0.f;
        unsigned short* hi_p = aT + c * 64;
        unsigned short* lo_p = aT + 128 * 64 + c * 64;
        #pragma unroll 8
        for (int k = 0; k < 64; ++k) {
            float w = W[k * 64 + cc];
            float a = gg[k] * w;
            unsigned short hi = f2bf(a);
            unsigned short lo = f2bf(a - bf2f(hi));
            hi_p[k] = hi; lo_p[k] = lo;
            s += a;
            cC = fmaf(bb[k], w, cC);
        }
        S[c] = s; C[c] = cC;
    } else {
        if (c < 64) {
            unsigned short* hi_p = fT + c * 64;
            unsigned short* lo_p = fT + 64 * 64 + c * 64;
            #pragma unroll 8
            for (int k = 0; k < 64; ++k) {
                float w = pw[k * 64 + c];
                unsigned short hi = f2bf(w);
                unsigned short lo = f2bf(w - bf2f(hi));
                hi_p[k] = hi; lo_p[k] = lo;
            }
            Cf[c] = pb[c];
        } else {
            for (int i = c - 64; i < NB; i += 64) bcnt[i] = 0;
        }
    }
}

// ---------------- MFMA node GEMM ----------------
// LN=true: out = rho*(h@A) - rho*mean*S + C; cols<64 -> xlb (bf16), cols>=64 -> xr (fp32).
// LN=false: out = h@A + C -> outp fp32 (in-place safe per 64-row tile).
template<int CTW, bool LN>
__global__ __launch_bounds__(256) void k_gemm(
    const float* __restrict__ h, const unsigned short* __restrict__ aT,
    const float* __restrict__ S, const float* __restrict__ C,
    unsigned short* __restrict__ xlb, float* __restrict__ xr, float* __restrict__ outp)
{
    __shared__ __align__(16) unsigned short hbh[64 * HS];
    __shared__ __align__(16) unsigned short hbl[64 * HS];
    __shared__ float smean[64], srho[64];
    const int tid = threadIdx.x;
    const int tile = blockIdx.x * 64;
    {
        const int row = tid >> 2, q = tid & 3;
        const int node = min(tile + row, NN - 1);
        const float* hp = h + (size_t)node * DD + q * 16;
        float4 v[4];
        #pragma unroll
        for (int i = 0; i < 4; ++i) v[i] = *(const float4*)(hp + i * 4);
        if (LN) {
            float sum = 0.f, ssq = 0.f;
            #pragma unroll
            for (int i = 0; i < 4; ++i) {
                sum += v[i].x + v[i].y + v[i].z + v[i].w;
                ssq += v[i].x * v[i].x + v[i].y * v[i].y + v[i].z * v[i].z + v[i].w * v[i].w;
            }
            sum += __shfl_xor(sum, 1, 64); ssq += __shfl_xor(ssq, 1, 64);
            sum += __shfl_xor(sum, 2, 64); ssq += __shfl_xor(ssq, 2, 64);
            if (q == 0) {
                float mean = sum * 0.015625f;
                float var = ssq * 0.015625f - mean * mean;
                smean[row] = mean;
                srho[row] = rsqrtf(var + 1e-5f);
            }
        }
        #pragma unroll
        for (int half = 0; half < 2; ++half) {
            bf16x8 ph, pl;
            #pragma unroll
            for (int e = 0; e < 8; ++e) {
                float f = (&v[half * 2 + (e >> 2)].x)[e & 3];
                unsigned short hi = f2bf(f);
                unsigned short lo = f2bf(f - bf2f(hi));
                ph[e] = (short)hi; pl[e] = (short)lo;
            }
            const int so = row * HS + q * 16 + half * 8;
            *(bf16x8*)&hbh[so] = ph;
            *(bf16x8*)&hbl[so] = pl;
        }
    }
    __syncthreads();
    const int lane = tid & 63;
    const int wslot = tid >> 6;
    const int li16 = lane & 15;
    const int g16 = lane >> 4;
    const int NCT = CTW * 4;
    f32x4 acc[CTW][4];
    #pragma unroll
    for (int c = 0; c < CTW; ++c)
        #pragma unroll
        for (int rt = 0; rt < 4; ++rt) acc[c][rt] = (f32x4){0.f, 0.f, 0.f, 0.f};
    #pragma unroll
    for (int kk = 0; kk < 2; ++kk) {
        bf16x8 ah[4], al[4];
        #pragma unroll
        for (int rt = 0; rt < 4; ++rt) {
            const int so = (rt * 16 + li16) * HS + kk * 32 + g16 * 8;
            ah[rt] = *(const bf16x8*)&hbh[so];
            al[rt] = *(const bf16x8*)&hbl[so];
        }
        #pragma unroll
        for (int c = 0; c < CTW; ++c) {
            const int ct = wslot + c * 4;
            const unsigned short* bp = aT + (ct * 16 + li16) * 64 + kk * 32 + g16 * 8;
            bf16x8 bh = *(const bf16x8*)bp;
            bf16x8 bl = *(const bf16x8*)(bp + NCT * 16 * 64);
            #pragma unroll
            for (int rt = 0; rt < 4; ++rt) {
                acc[c][rt] = __builtin_amdgcn_mfma_f32_16x16x32_bf16(ah[rt], bh, acc[c][rt], 0, 0, 0);
                acc[c][rt] = __builtin_amdgcn_mfma_f32_16x16x32_bf16(al[rt], bh, acc[c][rt], 0, 0, 0);
                acc[c][rt] = __builtin_amdgcn_mfma_f32_16x16x32_bf16(ah[rt], bl, acc[c][rt], 0, 0, 0);
            }
        }
    }
    #pragma unroll
    for (int c = 0; c < CTW; ++c) {
        const int ct = wslot + c * 4;
        const int col = ct * 16 + li16;
        const float Cc = C[col];
        float Sc = 0.f;
        if (LN) Sc = S[col];
        #pragma unroll
        for (int rt = 0; rt < 4; ++rt) {
            const int r0 = rt * 16 + g16 * 4;
            #pragma unroll
            for (int j = 0; j < 4; ++j) {
                const int row2 = r0 + j;
                const int node = tile + row2;
                if (node < NN) {
                    float p = acc[c][rt][j];
                    if (LN) {
                        float val = fmaf(srho[row2], p - smean[row2] * Sc, Cc);
                        if (ct < 4) xlb[(size_t)node * DD + col]       = f2bf(val);
                        else        xr[(size_t)node * DD + (col & 63)] = val;
                    } else {
                        outp[(size_t)node * DD + col] = p + Cc;
                    }
                }
            }
        }
    }
}

// ---------------- aggregation: one wave per target node, 16 lanes x 4 edges ----------------
// bf16 gather, 2-deep pipeline, DPP reduce, packed v_pk_f32 math, distributed epilogue.
__global__ __launch_bounds__(256) void k_agg(
    const int* __restrict__ rowptr, const int* __restrict__ csr,
    const unsigned short* __restrict__ xlb, const float* __restrict__ xr,
    const float* __restrict__ att, const float* __restrict__ cbias,
    const float* __restrict__ h_in, float* __restrict__ h_out)
{
    const int lane = threadIdx.x & 63;
    const int li   = lane & 15;     // feature-quad index
    const int sub  = lane >> 4;     // edge slot 0..3
    const int li4  = li * 4;
    const int fidx = li4 + sub;     // feature this lane owns in the epilogue
    const int wid  = (blockIdx.x * 256 + threadIdx.x) >> 6;
    const int nw   = gridDim.x * 4;
    const float L2E = 1.4426950408889634f;
    const float4 ar = *(const float4*)&att[li4];
    // leaky(t)*a = a*max(t,0) + 0.2a*min(t,0); log2e folded for exp2-domain softmax
    const f32x2 a1_01  = {L2E * ar.x, L2E * ar.y};
    const f32x2 a1_23  = {L2E * ar.z, L2E * ar.w};
    const f32x2 a02_01 = {0.2f * L2E * ar.x, 0.2f * L2E * ar.y};
    const f32x2 a02_23 = {0.2f * L2E * ar.z, 0.2f * L2E * ar.w};
    const float cb = cbias[fidx];
    const f32x2 z2 = {0.f, 0.f};
    for (int n = wid; n < NN; n += nw) {
        const float4 xq = *(const float4*)&xr[(size_t)n * DD + li4];
        const f32x2 xrt01 = {xq.x, xq.y};
        const f32x2 xrt23 = {xq.z, xq.w};
        const int beg = rowptr[n], end = rowptr[n + 1];   // len >= 1 (self first)
        const int end1 = end - 1;
        // 2-deep software pipeline on the bf16 gather (csr pre-scaled by 64)
        int j  = beg + sub;
        int jn = j + 4;
        unsigned o0 = (unsigned)csr[min(j,  end1)] + li4;
        uint2 v  = *(const uint2*)&xlb[o0];
        unsigned o1 = (unsigned)csr[min(jn, end1)] + li4;
        uint2 vn = *(const uint2*)&xlb[o1];
        float den = 0.f;
        f32x2 acc01 = z2, acc23 = z2;
        const int nch = (end - beg + 3) >> 2;
        for (int c = 0; c < nch; ++c) {
            const uint2 cur = v;
            const int jcur = j;
            v = vn;
            j = jn;
            jn += 4;
            unsigned o2 = (unsigned)csr[min(jn, end1)] + li4;
            vn = *(const uint2*)&xlb[o2];                    // prefetch c+2 (clamped)
            f32x2 f01, f23;
            f01.x = __uint_as_float(cur.x << 16);
            f01.y = __uint_as_float(cur.x & 0xFFFF0000u);
            f23.x = __uint_as_float(cur.y << 16);
            f23.y = __uint_as_float(cur.y & 0xFFFF0000u);
            const f32x2 t01 = f01 + xrt01;
            const f32x2 t23 = f23 + xrt23;
            f32x2 pv = __builtin_elementwise_max(t01, z2) * a1_01;
            pv = __builtin_elementwise_min(t01, z2) * a02_01 + pv;
            pv = __builtin_elementwise_max(t23, z2) * a1_23 + pv;
            pv = __builtin_elementwise_min(t23, z2) * a02_23 + pv;
            float p = row16_sum(pv.x + pv.y);
            float ex = (jcur < end) ? EXP2(p) : 0.f;
            den += ex;
            const f32x2 ex2 = {ex, ex};
            acc01 = f01 * ex2 + acc01;
            acc23 = f23 * ex2 + acc23;
        }
        // full butterfly across the 4 edge slots: all lanes get totals
        #pragma unroll
        for (int o = 16; o < 64; o <<= 1) {
            acc01.x += __shfl_xor(acc01.x, o, 64);
            acc01.y += __shfl_xor(acc01.y, o, 64);
            acc23.x += __shfl_xor(acc23.x, o, 64);
            acc23.y += __shfl_xor(acc23.y, o, 64);
            den     += __shfl_xor(den,     o, 64);
        }
        // distributed epilogue: each lane finishes ONE feature (1 erff chain, not 4)
        const float id = 1.f / (den + 1e-16f);
        const float v01 = (sub & 1) ? acc01.y : acc01.x;
        const float v23 = (sub & 1) ? acc23.y : acc23.x;
        const float val = (sub & 2) ? v23 : v01;
        const float o = gelu_exact(fmaf(val, id, cb)) + h_in[(size_t)n * DD + fidx];
        h_out[(size_t)n * DD + fidx] = o;
    }
}

extern "C" void kernel_launch(void* const* d_in, const int* in_sizes, int n_in,
                              void* d_out, int out_size, void* d_ws, size_t ws_size,
                              hipStream_t stream) {
    const int*   edge_index = (const int*)d_in[1];
    const int*   src   = edge_index;
    const int*   tgt   = edge_index + NE;
    const float* emb   = (const float*)d_in[2];
    const float* ln_g  = (const float*)d_in[3];
    const float* ln_b  = (const float*)d_in[4];
    const float* Wl    = (const float*)d_in[5];
    const float* Wr    = (const float*)d_in[6];
    const float* att   = (const float*)d_in[7];
    const float* cbias = (const float*)d_in[8];
    const float* pw    = (const float*)d_in[9];
    const float* pb    = (const float*)d_in[10];
    float* out = (float*)d_out;

    unsigned short* xlb = (unsigned short*)d_ws;           // NN*64 bf16
    float* xr = (float*)(xlb + (size_t)NN * DD);
    int* csr             = (int*)(xr + (size_t)NN * DD);   // NE+NN
    unsigned int* ebuf   = (unsigned int*)(csr + NE + NN);
    int* rowptr          = (int*)(ebuf + NE);              // NN+8
    int* bcnt            = rowptr + NN + 8;                // 392 (padded)
    int* bbase           = bcnt + 392;                     // 400 (padded)
    int* wbase           = bbase + 400;                    // 400 (padded)
    unsigned short* aT0  = (unsigned short*)(wbase + 400); // 2*128*64
    unsigned short* aT1  = aT0 + 2 * 128 * 64;
    unsigned short* fT   = aT1 + 2 * 128 * 64;             // 2*64*64
    float* S0 = (float*)(fT + 2 * 64 * 64);
    float* C0 = S0 + 128;
    float* S1 = C0 + 128;
    float* C1 = S1 + 128;
    float* Cf = C1 + 128;

    const int AGG_BLOCKS = 2048;

    // ---- fused weight precompute + bcnt zero ----
    k_wall<<<3, 128, 0, stream>>>(Wl, Wr, ln_g, ln_b, pw, pb,
                                  aT0, aT1, fT, S0, C0, S1, C1, Cf, bcnt);

    // ---- CSR build (two-level bucket sort by target, self-loops embedded) ----
    k_bcount<<<256, 256, 0, stream>>>(tgt, bcnt);
    k_bscan<<<1, 512, 0, stream>>>(bcnt, bbase, wbase);
    k_bscatter<<<(NE + SCH - 1) / SCH, 256, 0, stream>>>(src, tgt, wbase, ebuf);
    k_bfinal<<<NB, 256, 0, stream>>>(bbase, ebuf, rowptr, csr);

    // ---- layer 0 ----
    k_gemm<2, true><<<GB, 256, 0, stream>>>(emb, aT0, S0, C0, xlb, xr, nullptr);
    k_agg<<<AGG_BLOCKS, 256, 0, stream>>>(rowptr, csr, xlb, xr, att, cbias, emb, out);        // h1

    // ---- layer 1 ----
    k_gemm<2, true><<<GB, 256, 0, stream>>>(out, aT1, S1, C1, xlb, xr, nullptr);
    k_agg<<<AGG_BLOCKS, 256, 0, stream>>>(rowptr, csr, xlb, xr, att + DD, cbias + DD, out, out); // h2

    // ---- final projection (MFMA, in-place per row tile) ----
    k_gemm<1, false><<<GB, 256, 0, stream>>>(out, fT, nullptr, Cf, nullptr, nullptr, out);
}

// Round 12
// 218.188 us; speedup vs baseline: 1.3568x; 1.1086x over previous
//
#include <hip/hip_runtime.h>
#include <math.h>

#define NN 100000      // nodes
#define DD 64          // dim
#define NE 1200000     // edges (without self-loops)
#define NB 391         // buckets of 256 nodes
#define SCH 2048       // edges per scatter block
#define BCAP 4096      // per-bucket ebuf capacity (mean 3072, sigma 55 -> 18-sigma margin)
#define CCAP (BCAP + 256)   // per-bucket csr capacity (edges + self-loops)
#define GB ((NN + 63) / 64) // 1563 row tiles for GEMM
#define HS 88          // LDS row stride in shorts (176B: 16B-aligned, <=2-way banks)

typedef __attribute__((ext_vector_type(8))) short bf16x8;
typedef __attribute__((ext_vector_type(4))) float f32x4;
typedef __attribute__((ext_vector_type(2))) float f32x2;

#if __has_builtin(__builtin_amdgcn_exp2f)
#define EXP2(x) __builtin_amdgcn_exp2f(x)
#else
#define EXP2(x) exp2f(x)
#endif

__device__ __forceinline__ unsigned short f2bf(float x) {
    unsigned u = __float_as_uint(x);
    return (unsigned short)((u + 0x7FFFu + ((u >> 16) & 1u)) >> 16);   // RNE
}
__device__ __forceinline__ float bf2f(unsigned short b) {
    return __uint_as_float(((unsigned)b) << 16);
}

__device__ __forceinline__ float gelu_exact(float x) {
    return 0.5f * x * (1.0f + erff(x * 0.70710678118654752f));
}

// sum across each 16-lane row via DPP row_ror 1/2/4/8 (pure VALU, no DS)
__device__ __forceinline__ float row16_sum(float x) {
    int t;
    t = __builtin_amdgcn_update_dpp(0, __float_as_int(x), 0x121, 0xf, 0xf, true);
    x += __int_as_float(t);
    t = __builtin_amdgcn_update_dpp(0, __float_as_int(x), 0x122, 0xf, 0xf, true);
    x += __int_as_float(t);
    t = __builtin_amdgcn_update_dpp(0, __float_as_int(x), 0x124, 0xf, 0xf, true);
    x += __int_as_float(t);
    t = __builtin_amdgcn_update_dpp(0, __float_as_int(x), 0x128, 0xf, 0xf, true);
    x += __int_as_float(t);
    return x;
}

// ---------------- fused weight precompute + bucket-cursor init (one dispatch) ----------------
__global__ __launch_bounds__(128) void k_wall(
    const float* __restrict__ Wl, const float* __restrict__ Wr,
    const float* __restrict__ g, const float* __restrict__ be,
    const float* __restrict__ pw, const float* __restrict__ pb,
    unsigned short* __restrict__ aT0, unsigned short* __restrict__ aT1,
    unsigned short* __restrict__ fT,
    float* __restrict__ S0, float* __restrict__ C0,
    float* __restrict__ S1, float* __restrict__ C1, float* __restrict__ Cf,
    int* __restrict__ bkcur)
{
    const int blk = blockIdx.x;
    const int c = threadIdx.x;          // 0..127
    if (blk < 2) {
        const float* WL = Wl + blk * DD * DD;
        const float* WR = Wr + blk * DD * DD;
        const float* gg = g + blk * DD;
        const float* bb = be + blk * DD;
        unsigned short* aT = blk ? aT1 : aT0;
        float* S = blk ? S1 : S0;
        float* C = blk ? C1 : C0;
        const float* W = (c < 64) ? WL : WR;
        const int cc = c & 63;
        float s = 0.f, cC = 0.f;
        unsigned short* hi_p = aT + c * 64;
        unsigned short* lo_p = aT + 128 * 64 + c * 64;
        #pragma unroll 8
        for (int k = 0; k < 64; ++k) {
            float w = W[k * 64 + cc];
            float a = gg[k] * w;
            unsigned short hi = f2bf(a);
            unsigned short lo = f2bf(a - bf2f(hi));
            hi_p[k] = hi; lo_p[k] = lo;
            s += a;
            cC = fmaf(bb[k], w, cC);
        }
        S[c] = s; C[c] = cC;
    } else {
        if (c < 64) {
            unsigned short* hi_p = fT + c * 64;
            unsigned short* lo_p = fT + 64 * 64 + c * 64;
            #pragma unroll 8
            for (int k = 0; k < 64; ++k) {
                float w = pw[k * 64 + c];
                unsigned short hi = f2bf(w);
                unsigned short lo = f2bf(w - bf2f(hi));
                hi_p[k] = hi; lo_p[k] = lo;
            }
            Cf[c] = pb[c];
        } else {
            for (int i = c - 64; i < NB; i += 64) bkcur[i] = i * BCAP;  // segment cursors
        }
    }
}

// ---------------- bucket scatter: edges -> per-bucket ebuf segments ----------------
__global__ __launch_bounds__(256) void k_bscatter(const int* __restrict__ src, const int* __restrict__ tgt,
                                                  int* __restrict__ bkcur, unsigned int* __restrict__ ebuf) {
    __shared__ int stgt[SCH];
    __shared__ unsigned short srk[SCH];
    __shared__ int hist[NB];
    __shared__ int hbase[NB];
    const int base = blockIdx.x * SCH;
    const int cnt = min(SCH, NE - base);
    const int tid = threadIdx.x;
    for (int i = tid; i < NB; i += 256) hist[i] = 0;
    for (int i = tid; i < cnt; i += 256) stgt[i] = tgt[base + i];
    __syncthreads();
    for (int i = tid; i < cnt; i += 256)
        srk[i] = (unsigned short)atomicAdd(&hist[stgt[i] >> 8], 1);
    __syncthreads();
    for (int b = tid; b < NB; b += 256) {
        int c = hist[b];
        hbase[b] = c ? atomicAdd(&bkcur[b], c) : 0;
    }
    __syncthreads();
    for (int i = tid; i < cnt; i += 256) {
        int t = stgt[i];
        unsigned int e = ((unsigned int)src[base + i] << 8) | (unsigned int)(t & 255);
        ebuf[hbase[t >> 8] + (int)srk[i]] = e;
    }
}

// ---------------- MFMA node GEMM tile (device body, shared by two kernels) ----------------
// LN=true: out = rho*(h@A) - rho*mean*S + C; cols<64 -> xlb, cols>=64 -> xrb (both bf16).
// LN=false: out = h@A + C -> outp fp32 (in-place safe per 64-row tile).
template<int CTW, bool LN>
__device__ __forceinline__ void gemm_tile(
    const int tile, unsigned short* hbh, unsigned short* hbl,
    float* smean, float* srho,
    const float* __restrict__ h, const unsigned short* __restrict__ aT,
    const float* __restrict__ S, const float* __restrict__ C,
    unsigned short* __restrict__ xlb, unsigned short* __restrict__ xrb,
    float* __restrict__ outp)
{
    const int tid = threadIdx.x;
    {
        const int row = tid >> 2, q = tid & 3;
        const int node = min(tile + row, NN - 1);
        const float* hp = h + (size_t)node * DD + q * 16;
        float4 v[4];
        #pragma unroll
        for (int i = 0; i < 4; ++i) v[i] = *(const float4*)(hp + i * 4);
        if (LN) {
            float sum = 0.f, ssq = 0.f;
            #pragma unroll
            for (int i = 0; i < 4; ++i) {
                sum += v[i].x + v[i].y + v[i].z + v[i].w;
                ssq += v[i].x * v[i].x + v[i].y * v[i].y + v[i].z * v[i].z + v[i].w * v[i].w;
            }
            sum += __shfl_xor(sum, 1, 64); ssq += __shfl_xor(ssq, 1, 64);
            sum += __shfl_xor(sum, 2, 64); ssq += __shfl_xor(ssq, 2, 64);
            if (q == 0) {
                float mean = sum * 0.015625f;
                float var = ssq * 0.015625f - mean * mean;
                smean[row] = mean;
                srho[row] = rsqrtf(var + 1e-5f);
            }
        }
        #pragma unroll
        for (int half = 0; half < 2; ++half) {
            bf16x8 ph, pl;
            #pragma unroll
            for (int e = 0; e < 8; ++e) {
                float f = (&v[half * 2 + (e >> 2)].x)[e & 3];
                unsigned short hi = f2bf(f);
                unsigned short lo = f2bf(f - bf2f(hi));
                ph[e] = (short)hi; pl[e] = (short)lo;
            }
            const int so = row * HS + q * 16 + half * 8;
            *(bf16x8*)&hbh[so] = ph;
            *(bf16x8*)&hbl[so] = pl;
        }
    }
    __syncthreads();
    const int lane = tid & 63;
    const int wslot = tid >> 6;
    const int li16 = lane & 15;
    const int g16 = lane >> 4;
    const int NCT = CTW * 4;
    f32x4 acc[CTW][4];
    #pragma unroll
    for (int c = 0; c < CTW; ++c)
        #pragma unroll
        for (int rt = 0; rt < 4; ++rt) acc[c][rt] = (f32x4){0.f, 0.f, 0.f, 0.f};
    #pragma unroll
    for (int kk = 0; kk < 2; ++kk) {
        bf16x8 ah[4], al[4];
        #pragma unroll
        for (int rt = 0; rt < 4; ++rt) {
            const int so = (rt * 16 + li16) * HS + kk * 32 + g16 * 8;
            ah[rt] = *(const bf16x8*)&hbh[so];
            al[rt] = *(const bf16x8*)&hbl[so];
        }
        #pragma unroll
        for (int c = 0; c < CTW; ++c) {
            const int ct = wslot + c * 4;
            const unsigned short* bp = aT + (ct * 16 + li16) * 64 + kk * 32 + g16 * 8;
            bf16x8 bh = *(const bf16x8*)bp;
            bf16x8 bl = *(const bf16x8*)(bp + NCT * 16 * 64);
            #pragma unroll
            for (int rt = 0; rt < 4; ++rt) {
                acc[c][rt] = __builtin_amdgcn_mfma_f32_16x16x32_bf16(ah[rt], bh, acc[c][rt], 0, 0, 0);
                acc[c][rt] = __builtin_amdgcn_mfma_f32_16x16x32_bf16(al[rt], bh, acc[c][rt], 0, 0, 0);
                acc[c][rt] = __builtin_amdgcn_mfma_f32_16x16x32_bf16(ah[rt], bl, acc[c][rt], 0, 0, 0);
            }
        }
    }
    #pragma unroll
    for (int c = 0; c < CTW; ++c) {
        const int ct = wslot + c * 4;
        const int col = ct * 16 + li16;
        const float Cc = C[col];
        float Sc = 0.f;
        if (LN) Sc = S[col];
        #pragma unroll
        for (int rt = 0; rt < 4; ++rt) {
            const int r0 = rt * 16 + g16 * 4;
            #pragma unroll
            for (int j = 0; j < 4; ++j) {
                const int row2 = r0 + j;
                const int node = tile + row2;
                if (node < NN) {
                    float p = acc[c][rt][j];
                    if (LN) {
                        float val = fmaf(srho[row2], p - smean[row2] * Sc, Cc);
                        unsigned short* xb = (ct < 4) ? xlb : xrb;
                        xb[(size_t)node * DD + (col & 63)] = f2bf(val);
                    } else {
                        outp[(size_t)node * DD + col] = p + Cc;
                    }
                }
            }
        }
    }
}

// standalone GEMM kernel
template<int CTW, bool LN>
__global__ __launch_bounds__(256) void k_gemm(
    const float* __restrict__ h, const unsigned short* __restrict__ aT,
    const float* __restrict__ S, const float* __restrict__ C,
    unsigned short* __restrict__ xlb, unsigned short* __restrict__ xrb,
    float* __restrict__ outp)
{
    __shared__ __align__(16) unsigned short hbh[64 * HS];
    __shared__ __align__(16) unsigned short hbl[64 * HS];
    __shared__ float smean[64], srho[64];
    gemm_tile<CTW, LN>(blockIdx.x * 64, hbh, hbl, smean, srho,
                       h, aT, S, C, xlb, xrb, outp);
}

// ---------------- fused: bucket-finalize (blocks < NB) || layer-0 GEMM (rest) ----------------
__global__ __launch_bounds__(256) void k_bfg(
    const int* __restrict__ bkcur, const unsigned int* __restrict__ ebuf,
    int2* __restrict__ rowse, int* __restrict__ csr,
    const float* __restrict__ h, const unsigned short* __restrict__ aT,
    const float* __restrict__ S, const float* __restrict__ C,
    unsigned short* __restrict__ xlb, unsigned short* __restrict__ xrb)
{
    __shared__ __align__(16) unsigned short hbh[64 * HS];
    __shared__ __align__(16) unsigned short hbl[64 * HS];
    __shared__ float smean[64], srho[64];
    __shared__ int hist[256];
    __shared__ int pos[256];
    __shared__ int wsum[4];
    if (blockIdx.x < NB) {
        const int b = blockIdx.x, tid = threadIdx.x;
        const int bb = b * BCAP;
        const int be = bkcur[b];            // final cursor = bb + count
        hist[tid] = 0;
        __syncthreads();
        for (int i = bb + tid; i < be; i += 256) atomicAdd(&hist[ebuf[i] & 255u], 1);
        __syncthreads();
        const int v = hist[tid];
        const int lane = tid & 63, w = tid >> 6;
        int sc = v;
        #pragma unroll
        for (int o = 1; o < 64; o <<= 1) { int t = __shfl_up(sc, o, 64); if (lane >= o) sc += t; }
        if (lane == 63) wsum[w] = sc;
        __syncthreads();
        int off = 0;
        for (int k = 0; k < w; ++k) off += wsum[k];
        const int node = b * 256 + tid;
        const int rp = b * CCAP + off + sc - v + tid;   // +tid: self slots of preceding nodes
        if (node < NN) {
            rowse[node] = make_int2(rp, rp + 1 + v);    // [beg, end): self + deg edges
            csr[rp] = node << 6;                        // self-loop first (pre-scaled by DD)
        }
        pos[tid] = rp + 1;
        __syncthreads();
        for (int i = bb + tid; i < be; i += 256) {
            unsigned int e = ebuf[i];
            int p = atomicAdd(&pos[e & 255u], 1);
            csr[p] = (int)(e >> 8) << 6;                // pre-scaled by DD
        }
    } else {
        gemm_tile<2, true>((blockIdx.x - NB) * 64, hbh, hbl, smean, srho,
                           h, aT, S, C, xlb, xrb, nullptr);
    }
}

// ---------------- aggregation: one wave per target node, 16 lanes x 4 edges ----------------
// bf16 gathers, 3-deep pipeline, DPP reduce, packed math, distributed epilogue.
__global__ __launch_bounds__(256) void k_agg(
    const int2* __restrict__ rowse, const int* __restrict__ csr,
    const unsigned short* __restrict__ xlb, const unsigned short* __restrict__ xrb,
    const float* __restrict__ att, const float* __restrict__ cbias,
    const float* __restrict__ h_in, float* __restrict__ h_out)
{
    const int lane = threadIdx.x & 63;
    const int li   = lane & 15;     // feature-quad index
    const int sub  = lane >> 4;     // edge slot 0..3
    const int li4  = li * 4;
    const int fidx = li4 + sub;     // feature this lane owns in the epilogue
    const int wid  = (blockIdx.x * 256 + threadIdx.x) >> 6;
    const int nw   = gridDim.x * 4;
    const float L2E = 1.4426950408889634f;
    const float4 ar = *(const float4*)&att[li4];
    const f32x2 a1_01  = {L2E * ar.x, L2E * ar.y};
    const f32x2 a1_23  = {L2E * ar.z, L2E * ar.w};
    const f32x2 a02_01 = {0.2f * L2E * ar.x, 0.2f * L2E * ar.y};
    const f32x2 a02_23 = {0.2f * L2E * ar.z, 0.2f * L2E * ar.w};
    const float cb = cbias[fidx];
    const f32x2 z2 = {0.f, 0.f};
    for (int n = wid; n < NN; n += nw) {
        const uint2 xru = *(const uint2*)&xrb[(size_t)n * DD + li4];
        f32x2 xrt01, xrt23;
        xrt01.x = __uint_as_float(xru.x << 16);
        xrt01.y = __uint_as_float(xru.x & 0xFFFF0000u);
        xrt23.x = __uint_as_float(xru.y << 16);
        xrt23.y = __uint_as_float(xru.y & 0xFFFF0000u);
        const int2 se = rowse[n];
        const int beg = se.x, end = se.y;                 // len >= 1 (self first)
        const int end1 = end - 1;
        // 3-deep software pipeline on the bf16 gather (csr pre-scaled by 64)
        int j0 = beg + sub;
        int j1 = j0 + 4;
        int j2 = j0 + 8;
        uint2 v0 = *(const uint2*)&xlb[(unsigned)csr[min(j0, end1)] + li4];
        uint2 v1 = *(const uint2*)&xlb[(unsigned)csr[min(j1, end1)] + li4];
        uint2 v2 = *(const uint2*)&xlb[(unsigned)csr[min(j2, end1)] + li4];
        float den = 0.f;
        f32x2 acc01 = z2, acc23 = z2;
        const int nch = (end - beg + 3) >> 2;
        for (int c = 0; c < nch; ++c) {
            const uint2 cur = v0;
            const int jcur = j0;
            v0 = v1; v1 = v2;
            j0 = j1; j1 = j2; j2 += 4;
            v2 = *(const uint2*)&xlb[(unsigned)csr[min(j2, end1)] + li4];  // prefetch c+3
            f32x2 f01, f23;
            f01.x = __uint_as_float(cur.x << 16);
            f01.y = __uint_as_float(cur.x & 0xFFFF0000u);
            f23.x = __uint_as_float(cur.y << 16);
            f23.y = __uint_as_float(cur.y & 0xFFFF0000u);
            const f32x2 t01 = f01 + xrt01;
            const f32x2 t23 = f23 + xrt23;
            f32x2 pv = __builtin_elementwise_max(t01, z2) * a1_01;
            pv = __builtin_elementwise_min(t01, z2) * a02_01 + pv;
            pv = __builtin_elementwise_max(t23, z2) * a1_23 + pv;
            pv = __builtin_elementwise_min(t23, z2) * a02_23 + pv;
            float p = row16_sum(pv.x + pv.y);
            float ex = (jcur < end) ? EXP2(p) : 0.f;
            den += ex;
            const f32x2 ex2 = {ex, ex};
            acc01 = f01 * ex2 + acc01;
            acc23 = f23 * ex2 + acc23;
        }
        // full butterfly across the 4 edge slots: all lanes get totals
        #pragma unroll
        for (int o = 16; o < 64; o <<= 1) {
            acc01.x += __shfl_xor(acc01.x, o, 64);
            acc01.y += __shfl_xor(acc01.y, o, 64);
            acc23.x += __shfl_xor(acc23.x, o, 64);
            acc23.y += __shfl_xor(acc23.y, o, 64);
            den     += __shfl_xor(den,     o, 64);
        }
        // distributed epilogue: each lane finishes ONE feature
        const float id = 1.f / (den + 1e-16f);
        const float v01 = (sub & 1) ? acc01.y : acc01.x;
        const float v23 = (sub & 1) ? acc23.y : acc23.x;
        const float val = (sub & 2) ? v23 : v01;
        const float o = gelu_exact(fmaf(val, id, cb)) + h_in[(size_t)n * DD + fidx];
        h_out[(size_t)n * DD + fidx] = o;
    }
}

extern "C" void kernel_launch(void* const* d_in, const int* in_sizes, int n_in,
                              void* d_out, int out_size, void* d_ws, size_t ws_size,
                              hipStream_t stream) {
    const int*   edge_index = (const int*)d_in[1];
    const int*   src   = edge_index;
    const int*   tgt   = edge_index + NE;
    const float* emb   = (const float*)d_in[2];
    const float* ln_g  = (const float*)d_in[3];
    const float* ln_b  = (const float*)d_in[4];
    const float* Wl    = (const float*)d_in[5];
    const float* Wr    = (const float*)d_in[6];
    const float* att   = (const float*)d_in[7];
    const float* cbias = (const float*)d_in[8];
    const float* pw    = (const float*)d_in[9];
    const float* pb    = (const float*)d_in[10];
    float* out = (float*)d_out;

    unsigned short* xlb = (unsigned short*)d_ws;             // NN*64 bf16
    unsigned short* xrb = xlb + (size_t)NN * DD;             // NN*64 bf16
    int* csr            = (int*)(xrb + (size_t)NN * DD);     // NB*CCAP
    unsigned int* ebuf  = (unsigned int*)(csr + NB * CCAP);  // NB*BCAP
    int2* rowse         = (int2*)(ebuf + (size_t)NB * BCAP); // NN int2
    int* bkcur          = (int*)(rowse + NN);                // 400 (padded)
    unsigned short* aT0 = (unsigned short*)(bkcur + 400);    // 2*128*64
    unsigned short* aT1 = aT0 + 2 * 128 * 64;
    unsigned short* fT  = aT1 + 2 * 128 * 64;                // 2*64*64
    float* S0 = (float*)(fT + 2 * 64 * 64);
    float* C0 = S0 + 128;
    float* S1 = C0 + 128;
    float* C1 = S1 + 128;
    float* Cf = C1 + 128;

    const int AGG_BLOCKS = 2048;

    // D1: weight precompute + bucket cursor init
    k_wall<<<3, 128, 0, stream>>>(Wl, Wr, ln_g, ln_b, pw, pb,
                                  aT0, aT1, fT, S0, C0, S1, C1, Cf, bkcur);

    // D2: bucket scatter (edges -> per-bucket segments)
    k_bscatter<<<(NE + SCH - 1) / SCH, 256, 0, stream>>>(src, tgt, bkcur, ebuf);

    // D3: bucket finalize (CSR+rowse) || layer-0 GEMM, fused in one dispatch
    k_bfg<<<NB + GB, 256, 0, stream>>>(bkcur, ebuf, rowse, csr,
                                       emb, aT0, S0, C0, xlb, xrb);

    // D4: layer-0 aggregation -> h1 (out)
    k_agg<<<AGG_BLOCKS, 256, 0, stream>>>(rowse, csr, xlb, xrb, att, cbias, emb, out);

    // D5: layer-1 GEMM (h1 -> xlb, xrb)
    k_gemm<2, true><<<GB, 256, 0, stream>>>(out, aT1, S1, C1, xlb, xrb, nullptr);

    // D6: layer-1 aggregation -> h2 (out)
    k_agg<<<AGG_BLOCKS, 256, 0, stream>>>(rowse, csr, xlb, xrb, att + DD, cbias + DD, out, out);

    // D7: final projection (MFMA, in-place per row tile)
    k_gemm<1, false><<<GB, 256, 0, stream>>>(out, fT, nullptr, Cf, nullptr, nullptr, out);
}